// Round 8
// baseline (315.876 us; speedup 1.0000x reference)
//
#include <hip/hip_runtime.h>
#include <hip/hip_bf16.h>

#define BS 8
#define D 512
#define CCH 128
#define LMAP 8
#define NLAYERS 9

typedef short short8 __attribute__((ext_vector_type(8)));
typedef short short4v __attribute__((ext_vector_type(4)));
typedef float f32x4 __attribute__((ext_vector_type(4)));

// ---- module-global scratch ----
// activations: bf16 NHWC [b][px][ci]
__device__ short g_bufA[(size_t)BS * 4096 * CCH];   // 8.4 MB
__device__ short g_bufB[(size_t)BS * 4096 * CCH];   // 8.4 MB
__device__ float g_w[BS * D];
__device__ float g_style_all[NLAYERS * BS * CCH];
__device__ float g_rstd_all[NLAYERS * BS * CCH];
// packed bf16 weight fragments: [layer][tap][chunk4][cogrp8][lane64][8]
__device__ short g_wpack[(size_t)NLAYERS * 9 * 4 * 8 * 64 * 8];   // 2.65 MB
// rgb: [tap][chunk4][lane64][8] (M=16 rows, rows 0-2 real)
__device__ short g_rgbpack[9 * 4 * 64 * 8];

__device__ __forceinline__ float leaky(float v) { return v >= 0.f ? v : 0.2f * v; }
__device__ __forceinline__ short f2b(float f) {
    __hip_bfloat16 h = __float2bfloat16(f);
    return *reinterpret_cast<short*>(&h);
}
__device__ __forceinline__ float b2f(short s) {
    return __uint_as_float(((unsigned int)(unsigned short)s) << 16);
}
// bank swizzle on short-index bits 3..5 (keeps 8-short blocks intact)
__device__ __forceinline__ int swz(int col) { return ((col ^ (col >> 3)) & 7) << 3; }

// upsample tap params (jax half-pixel + boundary renorm), per axis
__device__ __forceinline__ void uptaps(int o, int Win, int& i0, int& i1, float& w0, float& w1)
{
    int m = o >> 1;
    if ((o & 1) == 0) { i0 = m - 1; i1 = m; w0 = 0.25f; w1 = 0.75f; if (i0 < 0) { i0 = 0; w0 = 0.f; w1 = 1.f; } }
    else              { i0 = m; i1 = m + 1; w0 = 0.75f; w1 = 0.25f; if (i1 >= Win) { i1 = Win - 1; w0 = 1.f; w1 = 0.f; } }
}

// ---------------- weight fragment prep ----------------
__global__ __launch_bounds__(256) void wprep_kernel(const float* __restrict__ convw)
{
    int idx = blockIdx.x * 256 + threadIdx.x;        // [layer][tap][chunk][cogrp][lane]
    if (idx >= NLAYERS * 9 * 4 * 8 * 64) return;
    int lane = idx & 63;
    int cogrp = (idx >> 6) & 7;
    int chunk = (idx >> 9) & 3;
    int t = idx >> 11;
    int layer = t / 9, tap = t - layer * 9;
    int co = cogrp * 16 + (lane & 15);
    int ci0 = chunk * 32 + (lane >> 4) * 8;
    short8 v;
#pragma unroll
    for (int j = 0; j < 8; ++j)
        v[j] = f2b(convw[(((size_t)layer * CCH + co) * CCH + ci0 + j) * 9 + tap]);
    *reinterpret_cast<short8*>(&g_wpack[(size_t)idx * 8]) = v;
}

__global__ void rgbprep_kernel(const float* __restrict__ rgbw)
{
    int idx = blockIdx.x * 256 + threadIdx.x;        // [tap][chunk][lane]
    if (idx >= 9 * 4 * 64) return;
    int lane = idx & 63;
    int chunk = (idx >> 6) & 3;
    int tap = idx >> 8;
    int co = lane & 15;
    int ci0 = chunk * 32 + (lane >> 4) * 8;
    short8 v;
#pragma unroll
    for (int j = 0; j < 8; ++j)
        v[j] = (co < 3) ? f2b(rgbw[((size_t)(co * CCH) + ci0 + j) * 9 + tap]) : (short)0;
    *reinterpret_cast<short8*>(&g_rgbpack[(size_t)idx * 8]) = v;
}

// ---------------- fused mapping MLP: pixelnorm + 8x FC+leaky, one block per batch ----------------
__global__ __launch_bounds__(256) void map_all_kernel(
    const float* __restrict__ z, const float* __restrict__ Wall, const float* __restrict__ ball)
{
    const int b = blockIdx.x;
    const int tid = threadIdx.x;
    __shared__ float wbuf[2][D];
    __shared__ float wred[4];

    // pixelnorm
    float v0 = z[b * D + tid], v1 = z[b * D + tid + 256];
    float p = v0 * v0 + v1 * v1;
#pragma unroll
    for (int off = 32; off > 0; off >>= 1) p += __shfl_down(p, off, 64);
    if ((tid & 63) == 0) wred[tid >> 6] = p;
    __syncthreads();
    float ss = wred[0] + wred[1] + wred[2] + wred[3];
    float r = rsqrtf(ss * (1.f / 512.f) + 1e-8f);
    wbuf[0][tid] = v0 * r;
    wbuf[0][tid + 256] = v1 * r;
    __syncthreads();

    for (int l = 0; l < LMAP; ++l) {
        const float* src = wbuf[l & 1];
        float* dst = wbuf[(l & 1) ^ 1];
        const float* Wc = Wall + (size_t)l * D * D + tid;   // column j0 = tid
        float a0 = 0.f, a1 = 0.f, a2 = 0.f, a3 = 0.f;
        float c0 = 0.f, c1 = 0.f, c2 = 0.f, c3 = 0.f;
        for (int k = 0; k < D; k += 4) {
            float x0 = src[k], x1 = src[k + 1], x2 = src[k + 2], x3 = src[k + 3];
            a0 += x0 * Wc[(size_t)(k + 0) * D];
            a1 += x1 * Wc[(size_t)(k + 1) * D];
            a2 += x2 * Wc[(size_t)(k + 2) * D];
            a3 += x3 * Wc[(size_t)(k + 3) * D];
            c0 += x0 * Wc[(size_t)(k + 0) * D + 256];
            c1 += x1 * Wc[(size_t)(k + 1) * D + 256];
            c2 += x2 * Wc[(size_t)(k + 2) * D + 256];
            c3 += x3 * Wc[(size_t)(k + 3) * D + 256];
        }
        __syncthreads();   // everyone done reading src before overwrite of dst (dst != src, but keep order)
        dst[tid] = leaky((a0 + a1) + (a2 + a3) + ball[l * D + tid]);
        dst[tid + 256] = leaky((c0 + c1) + (c2 + c3) + ball[l * D + tid + 256]);
        __syncthreads();
    }
    g_w[b * D + tid] = wbuf[0][tid];
    g_w[b * D + tid + 256] = wbuf[0][tid + 256];
}

// ---------------- style + rstd for ALL layers, one dispatch ----------------
__global__ __launch_bounds__(256) void style_rstd_kernel(
    const float* __restrict__ Aw, const float* __restrict__ Ab,
    const float* __restrict__ convw)
{
    int l = blockIdx.x + 1;        // layers 1..8
    int b = blockIdx.y;
    int tid = threadIdx.x;
    __shared__ float ws_[D];
    __shared__ float part[2][CCH];
    __shared__ float st[CCH];
    ws_[tid] = g_w[b * D + tid];
    ws_[tid + 256] = g_w[b * D + tid + 256];
    __syncthreads();
    {
        int c = tid & 127, kh = tid >> 7;
        const float* Ap = Aw + (size_t)l * D * CCH + c;
        const int k0 = kh * 256;
        float a0 = 0.f, a1 = 0.f, a2 = 0.f, a3 = 0.f, a4 = 0.f, a5 = 0.f, a6 = 0.f, a7 = 0.f;
        for (int k = k0; k < k0 + 256; k += 8) {
            a0 += ws_[k + 0] * Ap[(size_t)(k + 0) * CCH];
            a1 += ws_[k + 1] * Ap[(size_t)(k + 1) * CCH];
            a2 += ws_[k + 2] * Ap[(size_t)(k + 2) * CCH];
            a3 += ws_[k + 3] * Ap[(size_t)(k + 3) * CCH];
            a4 += ws_[k + 4] * Ap[(size_t)(k + 4) * CCH];
            a5 += ws_[k + 5] * Ap[(size_t)(k + 5) * CCH];
            a6 += ws_[k + 6] * Ap[(size_t)(k + 6) * CCH];
            a7 += ws_[k + 7] * Ap[(size_t)(k + 7) * CCH];
        }
        part[kh][c] = ((a0 + a1) + (a2 + a3)) + ((a4 + a5) + (a6 + a7));
    }
    __syncthreads();
    if (tid < CCH) {
        float s = part[0][tid] + part[1][tid] + Ab[l * CCH + tid];
        st[tid] = s;
        g_style_all[((size_t)l * BS + b) * CCH + tid] = s;
    }
    __syncthreads();
    int colid = tid >> 4, kpart = tid & 15;
    for (int co8 = 0; co8 < 8; ++co8) {
        int cout = co8 * 16 + colid;
        const float* wp = convw + ((size_t)(l * CCH + cout) * CCH + kpart * 8) * 9;
        float wf[72];
#pragma unroll
        for (int q = 0; q < 18; ++q) {
            float4 t = *reinterpret_cast<const float4*>(wp + q * 4);
            wf[q * 4 + 0] = t.x; wf[q * 4 + 1] = t.y; wf[q * 4 + 2] = t.z; wf[q * 4 + 3] = t.w;
        }
        float s = 0.f;
#pragma unroll
        for (int ci = 0; ci < 8; ++ci) {
            float sv = st[kpart * 8 + ci];
#pragma unroll
            for (int k = 0; k < 9; ++k) { float m = wf[ci * 9 + k] * sv; s += m * m; }
        }
#pragma unroll
        for (int off = 8; off > 0; off >>= 1) s += __shfl_down(s, off, 16);
        if (kpart == 0) g_rstd_all[((size_t)l * BS + b) * CCH + cout] = rsqrtf(s + 1e-8f);
    }
}

// ---------------- MFMA modulated conv (NHWC bf16 in/out) ----------------
// Block: 64 px (full-width row band) x ALL 128 co; 4 waves; wave owns 2 co-frags.
// UPM: 0 = plain copy staging; 1 = fused bilinear 2x upsample from half-res buffer;
//      2 = fused upsample from layer-0 mini-tile computed from noise (i==1).
// Epilogue folds style of layerNext (0 = none).
template<int LW, int UPM>
__global__ __launch_bounds__(256) void conv_mfma_kernel(
    int srcSel, int layer, int layerNext,
    const float* __restrict__ noise,
    const float* __restrict__ Bw, const float* __restrict__ Bb,
    const float* __restrict__ noise0,
    const float* __restrict__ Bw0, const float* __restrict__ Bb0)
{
    constexpr int W = 1 << LW;
    constexpr int R = 64 >> LW;
    constexpr int SW = W + 2;
    constexpr int ROWS = R + 2;
    constexpr int NS = W * W;
    constexpr int WIN = W / 2;          // source res for UPM 1/2

    const short* xin = srcSel ? g_bufB : g_bufA;
    short* xout = srcSel ? g_bufA : g_bufB;

    const int b = blockIdx.y;
    const int pixBase = blockIdx.x * 64;
    const int rowBase = pixBase >> LW;
    const int tid = threadIdx.x;
    const int lane = tid & 63;
    const int wave = tid >> 6;

    __shared__ short xs[ROWS * SW * CCH];
    __shared__ float style_s[CCH];
    constexpr int SMSZ = (UPM == 2) ? 16 * CCH : 1;
    __shared__ short sm[SMSZ];

    if (tid < CCH)
        style_s[tid] = layerNext ? g_style_all[((size_t)layerNext * BS + b) * CCH + tid] : 1.f;

    if (UPM == 2) {
        // layer-0 source tile: leaky(noise0*Bw0+Bb0) * style[1], 4x4 NHWC bf16
        for (int u = tid; u < 16 * CCH; u += 256) {
            int c = u & 127;
            int pp = u >> 7;
            float v = leaky(noise0[b * 4096 + pp] * Bw0[c] + Bb0[c])
                      * g_style_all[((size_t)1 * BS + b) * CCH + c];
            sm[u] = f2b(v);
        }
        __syncthreads();
    }

    // ---- stage x into swizzled LDS ----
    {
        const short* src = xin + (size_t)b * NS * CCH;          // UPM0
        const short* srcH = xin + (size_t)b * WIN * WIN * CCH;  // UPM1
        constexpr int UN = ROWS * SW * 16;
        for (int u = tid; u < UN; u += 256) {
            int ck = u & 15;
            int rem = u >> 4;
            int col = rem % SW;
            int rr = rem / SW;
            int gy = rowBase + rr - 1, gx = col - 1;
            short8 v = {0, 0, 0, 0, 0, 0, 0, 0};
            if (gy >= 0 && gy < W && gx >= 0 && gx < W) {
                if (UPM == 0) {
                    v = *reinterpret_cast<const short8*>(&src[((size_t)gy * W + gx) * CCH + ck * 8]);
                } else {
                    int y0, y1, x0, x1; float wy0, wy1, wx0, wx1;
                    uptaps(gy, WIN, y0, y1, wy0, wy1);
                    uptaps(gx, WIN, x0, x1, wx0, wx1);
                    const short* sp = (UPM == 2) ? sm : srcH;
                    short8 a00 = *reinterpret_cast<const short8*>(&sp[((size_t)y0 * WIN + x0) * CCH + ck * 8]);
                    short8 a01 = *reinterpret_cast<const short8*>(&sp[((size_t)y0 * WIN + x1) * CCH + ck * 8]);
                    short8 a10 = *reinterpret_cast<const short8*>(&sp[((size_t)y1 * WIN + x0) * CCH + ck * 8]);
                    short8 a11 = *reinterpret_cast<const short8*>(&sp[((size_t)y1 * WIN + x1) * CCH + ck * 8]);
                    float w00 = wy0 * wx0, w01 = wy0 * wx1, w10 = wy1 * wx0, w11 = wy1 * wx1;
#pragma unroll
                    for (int j = 0; j < 8; ++j)
                        v[j] = f2b(w00 * b2f(a00[j]) + w01 * b2f(a01[j])
                                 + w10 * b2f(a10[j]) + w11 * b2f(a11[j]));
                }
            }
            *reinterpret_cast<short8*>(&xs[(((rr * SW + col) * CCH) + ck * 8) ^ swz(col)]) = v;
        }
    }
    __syncthreads();

    int rL[4], cL[4];
#pragma unroll
    for (int pf = 0; pf < 4; ++pf) {
        int pl = pf * 16 + (lane & 15);
        cL[pf] = pl & (W - 1);
        rL[pf] = pl >> LW;
    }
    const int grpoff = (lane >> 4) * 8;

    f32x4 acc[2][4] = {};
    const short* wl0 = g_wpack + ((size_t)layer * 9 * 4 * 8 * 64
                                  + (size_t)(wave * 2) * 64 + lane) * 8;
    const short* wl1 = wl0 + 64 * 8;

    short8 wc0 = *reinterpret_cast<const short8*>(wl0);
    short8 wc1 = *reinterpret_cast<const short8*>(wl1);
#pragma unroll
    for (int k = 0; k < 36; ++k) {
        short8 wn0 = wc0, wn1 = wc1;
        if (k + 1 < 36) {
            wn0 = *reinterpret_cast<const short8*>(wl0 + (size_t)(k + 1) * 4096);
            wn1 = *reinterpret_cast<const short8*>(wl1 + (size_t)(k + 1) * 4096);
        }
        const int tap = k >> 2, ch = k & 3;
        const int ky = tap / 3, kx = tap - ky * 3;
#pragma unroll
        for (int pf = 0; pf < 4; ++pf) {
            int col = cL[pf] + kx;
            int idx = (((rL[pf] + ky) * SW + col) * CCH + (ch << 5) + grpoff) ^ swz(col);
            short8 xf = *reinterpret_cast<const short8*>(&xs[idx]);
            acc[0][pf] = __builtin_amdgcn_mfma_f32_16x16x32_bf16(wc0, xf, acc[0][pf], 0, 0, 0);
            acc[1][pf] = __builtin_amdgcn_mfma_f32_16x16x32_bf16(wc1, xf, acc[1][pf], 0, 0, 0);
        }
        wc0 = wn0; wc1 = wn1;
    }

    // ---- epilogue: demod + noise + leaky, fold next style, bf16 NHWC short4 stores ----
    float nz[4];
#pragma unroll
    for (int pf = 0; pf < 4; ++pf)
        nz[pf] = noise[b * 4096 + pixBase + pf * 16 + (lane & 15)];
#pragma unroll
    for (int cf = 0; cf < 2; ++cf) {
        const int coB = (wave * 2 + cf) * 16 + (lane >> 4) * 4;
        float rs[4], bw[4], bb[4], sn[4];
#pragma unroll
        for (int r = 0; r < 4; ++r) {
            rs[r] = g_rstd_all[((size_t)layer * BS + b) * CCH + coB + r];
            bw[r] = Bw[coB + r];
            bb[r] = Bb[coB + r];
            sn[r] = style_s[coB + r];
        }
#pragma unroll
        for (int pf = 0; pf < 4; ++pf) {
            int px = pixBase + pf * 16 + (lane & 15);
            short4v o;
#pragma unroll
            for (int r = 0; r < 4; ++r) {
                float v = leaky(acc[cf][pf][r] * rs[r] + nz[pf] * bw[r] + bb[r]) * sn[r];
                o[r] = f2b(v);
            }
            *reinterpret_cast<short4v*>(&xout[((size_t)b * NS + px) * CCH + coB]) = o;
        }
    }
}

// ---------------- MFMA toRGB (W=64; 3 real rows in 16-row M tile; waves split K) ----------------
__global__ __launch_bounds__(256) void rgb_mfma_kernel(
    int srcSel, const float* __restrict__ rgbb, float* __restrict__ out)
{
    constexpr int W = 64, SW = 66, ROWS = 3, NS = 4096;
    const short* xin = srcSel ? g_bufB : g_bufA;

    const int b = blockIdx.y;
    const int pixBase = blockIdx.x * 64;
    const int rowBase = pixBase >> 6;
    const int tid = threadIdx.x;
    const int lane = tid & 63;
    const int wave = tid >> 6;     // K-chunk

    __shared__ short xs[ROWS * SW * CCH];

    {
        const short* src = xin + (size_t)b * NS * CCH;
        constexpr int UN = ROWS * SW * 16;
        for (int u = tid; u < UN; u += 256) {
            int ck = u & 15;
            int rem = u >> 4;
            int col = rem % SW;
            int rr = rem / SW;
            int gy = rowBase + rr - 1, gx = col - 1;
            short8 v = {0, 0, 0, 0, 0, 0, 0, 0};
            if (gy >= 0 && gy < W && gx >= 0 && gx < W)
                v = *reinterpret_cast<const short8*>(&src[((size_t)gy * W + gx) * CCH + ck * 8]);
            *reinterpret_cast<short8*>(&xs[(((rr * SW + col) * CCH) + ck * 8) ^ swz(col)]) = v;
        }
    }
    __syncthreads();

    const int grpoff = (lane >> 4) * 8;
    const int cl = lane & 15;
    f32x4 acc[4] = {};
#pragma unroll
    for (int tap = 0; tap < 9; ++tap) {
        const int ky = tap / 3, kx = tap - ky * 3;
        short8 wf = *reinterpret_cast<const short8*>(
            &g_rgbpack[((size_t)(tap * 4 + wave) * 64 + lane) * 8]);
#pragma unroll
        for (int pf = 0; pf < 4; ++pf) {
            int col = cl + pf * 16 + kx;
            int idx = ((ky * SW + col) * CCH + (wave << 5) + grpoff) ^ swz(col);
            short8 xf = *reinterpret_cast<const short8*>(&xs[idx]);
            acc[pf] = __builtin_amdgcn_mfma_f32_16x16x32_bf16(wf, xf, acc[pf], 0, 0, 0);
        }
    }
    __syncthreads();
    float* red = reinterpret_cast<float*>(xs);   // reuse LDS for K-reduction
    if (wave > 0) {
#pragma unroll
        for (int pf = 0; pf < 4; ++pf)
#pragma unroll
            for (int r = 0; r < 4; ++r)
                red[(((wave - 1) * 4 + pf) * 64 + lane) * 4 + r] = acc[pf][r];
    }
    __syncthreads();
    if (wave == 0 && (lane >> 4) == 0) {
#pragma unroll
        for (int pf = 0; pf < 4; ++pf) {
            int px = pixBase + pf * 16 + cl;
#pragma unroll
            for (int r = 0; r < 3; ++r) {
                float s = acc[pf][r];
#pragma unroll
                for (int wv = 0; wv < 3; ++wv)
                    s += red[((wv * 4 + pf) * 64 + lane) * 4 + r];
                out[(size_t)(b * 3 + r) * NS + px] = s + rgbb[r];
            }
        }
    }
}

// ---------------- launch ----------------
extern "C" void kernel_launch(void* const* d_in, const int* in_sizes, int n_in,
                              void* d_out, int out_size, void* d_ws, size_t ws_size,
                              hipStream_t stream)
{
    const float* latent = (const float*)d_in[0];
    const float* noise  = (const float*)d_in[1];
    const float* map_w  = (const float*)d_in[2];
    const float* map_b  = (const float*)d_in[3];
    const float* A_w    = (const float*)d_in[4];
    const float* A_b    = (const float*)d_in[5];
    const float* B_w    = (const float*)d_in[6];
    const float* B_b    = (const float*)d_in[7];
    const float* conv_w = (const float*)d_in[8];
    const float* rgb_w  = (const float*)d_in[9];
    const float* rgb_b  = (const float*)d_in[10];
    float* out = (float*)d_out;
    (void)d_ws; (void)ws_size;

    wprep_kernel<<<(NLAYERS * 9 * 4 * 8 * 64 + 255) / 256, 256, 0, stream>>>(conv_w);
    rgbprep_kernel<<<(9 * 4 * 64 + 255) / 256, 256, 0, stream>>>(rgb_w);

    map_all_kernel<<<BS, 256, 0, stream>>>(latent, map_w, map_b);
    style_rstd_kernel<<<dim3(8, BS), 256, 0, stream>>>(A_w, A_b, conv_w);

    int cur = 1;   // pretend data in B so conv1 writes A
    int Hc = 4;
    for (int i = 1; i < NLAYERS; ++i) {
        if (i & 1) Hc *= 2;    // upsample is fused into the conv for odd i
        int ns = Hc * Hc;
        int lnext = (i < 8) ? (i + 1) : 0;
        dim3 grid(ns / 64, BS);
        const float* nz = noise + (size_t)i * BS * 4096;
        switch (i) {
            case 1: conv_mfma_kernel<3, 2><<<grid, 256, 0, stream>>>(cur, i, lnext, nz, B_w + i * CCH, B_b + i * CCH, noise, B_w, B_b); break;
            case 2: conv_mfma_kernel<3, 0><<<grid, 256, 0, stream>>>(cur, i, lnext, nz, B_w + i * CCH, B_b + i * CCH, noise, B_w, B_b); break;
            case 3: conv_mfma_kernel<4, 1><<<grid, 256, 0, stream>>>(cur, i, lnext, nz, B_w + i * CCH, B_b + i * CCH, noise, B_w, B_b); break;
            case 4: conv_mfma_kernel<4, 0><<<grid, 256, 0, stream>>>(cur, i, lnext, nz, B_w + i * CCH, B_b + i * CCH, noise, B_w, B_b); break;
            case 5: conv_mfma_kernel<5, 1><<<grid, 256, 0, stream>>>(cur, i, lnext, nz, B_w + i * CCH, B_b + i * CCH, noise, B_w, B_b); break;
            case 6: conv_mfma_kernel<5, 0><<<grid, 256, 0, stream>>>(cur, i, lnext, nz, B_w + i * CCH, B_b + i * CCH, noise, B_w, B_b); break;
            case 7: conv_mfma_kernel<6, 1><<<grid, 256, 0, stream>>>(cur, i, lnext, nz, B_w + i * CCH, B_b + i * CCH, noise, B_w, B_b); break;
            case 8: conv_mfma_kernel<6, 0><<<grid, 256, 0, stream>>>(cur, i, lnext, nz, B_w + i * CCH, B_b + i * CCH, noise, B_w, B_b); break;
        }
        cur ^= 1;
    }

    rgb_mfma_kernel<<<dim3(64, BS), 256, 0, stream>>>(cur, rgb_b, out);
}

// Round 9
// 245.870 us; speedup vs baseline: 1.2847x; 1.2847x over previous
//
#include <hip/hip_runtime.h>
#include <hip/hip_bf16.h>

#define BS 8
#define D 512
#define CCH 128
#define LMAP 8
#define NLAYERS 9

typedef short short8 __attribute__((ext_vector_type(8)));
typedef short short4v __attribute__((ext_vector_type(4)));
typedef float f32x4 __attribute__((ext_vector_type(4)));

// ---- module-global scratch ----
// activations: bf16 NHWC [b][px][ci]
__device__ short g_bufA[(size_t)BS * 4096 * CCH];   // 8.4 MB
__device__ short g_bufB[(size_t)BS * 4096 * CCH];   // 8.4 MB
__device__ float g_w[2][BS * D];
__device__ float g_style_all[NLAYERS * BS * CCH];
__device__ float g_rstd_all[NLAYERS * BS * CCH];
// packed bf16 weight fragments: [layer][tap][chunk4][cogrp8][lane64][8]
__device__ short g_wpack[(size_t)NLAYERS * 9 * 4 * 8 * 64 * 8];   // 2.65 MB
// rgb: [tap][chunk4][lane64][8] (M=16 rows, rows 0-2 real)
__device__ short g_rgbpack[9 * 4 * 64 * 8];

__device__ __forceinline__ float leaky(float v) { return v >= 0.f ? v : 0.2f * v; }
__device__ __forceinline__ short f2b(float f) {
    __hip_bfloat16 h = __float2bfloat16(f);
    return *reinterpret_cast<short*>(&h);
}
__device__ __forceinline__ float b2f(short s) {
    return __uint_as_float(((unsigned int)(unsigned short)s) << 16);
}
// bank swizzle on short-index bits 3..5 (keeps 8-short blocks intact)
__device__ __forceinline__ int swz(int col) { return ((col ^ (col >> 3)) & 7) << 3; }

// upsample tap params (jax half-pixel + boundary renorm), per axis
__device__ __forceinline__ void uptaps(int o, int Win, int& i0, int& i1, float& w0, float& w1)
{
    int m = o >> 1;
    if ((o & 1) == 0) { i0 = m - 1; i1 = m; w0 = 0.25f; w1 = 0.75f; if (i0 < 0) { i0 = 0; w0 = 0.f; w1 = 1.f; } }
    else              { i0 = m; i1 = m + 1; w0 = 0.75f; w1 = 0.25f; if (i1 >= Win) { i1 = Win - 1; w0 = 1.f; w1 = 0.f; } }
}

// ---------------- weight fragment prep ----------------
__global__ __launch_bounds__(256) void wprep_kernel(const float* __restrict__ convw)
{
    int idx = blockIdx.x * 256 + threadIdx.x;        // [layer][tap][chunk][cogrp][lane]
    if (idx >= NLAYERS * 9 * 4 * 8 * 64) return;
    int lane = idx & 63;
    int cogrp = (idx >> 6) & 7;
    int chunk = (idx >> 9) & 3;
    int t = idx >> 11;
    int layer = t / 9, tap = t - layer * 9;
    int co = cogrp * 16 + (lane & 15);
    int ci0 = chunk * 32 + (lane >> 4) * 8;
    short8 v;
#pragma unroll
    for (int j = 0; j < 8; ++j)
        v[j] = f2b(convw[(((size_t)layer * CCH + co) * CCH + ci0 + j) * 9 + tap]);
    *reinterpret_cast<short8*>(&g_wpack[(size_t)idx * 8]) = v;
}

__global__ void rgbprep_kernel(const float* __restrict__ rgbw)
{
    int idx = blockIdx.x * 256 + threadIdx.x;        // [tap][chunk][lane]
    if (idx >= 9 * 4 * 64) return;
    int lane = idx & 63;
    int chunk = (idx >> 6) & 3;
    int tap = idx >> 8;
    int co = lane & 15;
    int ci0 = chunk * 32 + (lane >> 4) * 8;
    short8 v;
#pragma unroll
    for (int j = 0; j < 8; ++j)
        v[j] = (co < 3) ? f2b(rgbw[((size_t)(co * CCH) + ci0 + j) * 9 + tap]) : (short)0;
    *reinterpret_cast<short8*>(&g_rgbpack[(size_t)idx * 8]) = v;
}

// ---------------- Mapping FC (round-7 proven: 64 blocks/layer, pixelnorm in layer 0) ----------------
__global__ __launch_bounds__(256) void map_fc_kernel(
    int srcSel, int useZ, const float* __restrict__ z,
    const float* __restrict__ W, const float* __restrict__ bias)
{
    float* wout = g_w[srcSel ^ 1];
    int b = blockIdx.y;
    int jb = blockIdx.x * 64;
    int tid = threadIdx.x;
    int jl = tid & 63, kp = tid >> 6;
    __shared__ float xin[D];
    __shared__ float part[4][64];
    __shared__ float wred[4];
    if (useZ) {
        xin[tid] = z[b * D + tid];
        xin[tid + 256] = z[b * D + tid + 256];
    } else {
        const float* win = g_w[srcSel];
        xin[tid] = win[b * D + tid];
        xin[tid + 256] = win[b * D + tid + 256];
    }
    __syncthreads();
    if (useZ) {
        float p = xin[tid] * xin[tid] + xin[tid + 256] * xin[tid + 256];
#pragma unroll
        for (int off = 32; off > 0; off >>= 1) p += __shfl_down(p, off, 64);
        if ((tid & 63) == 0) wred[tid >> 6] = p;
        __syncthreads();
        float ss = wred[0] + wred[1] + wred[2] + wred[3];
        float r = rsqrtf(ss * (1.f / 512.f) + 1e-8f);
        xin[tid] *= r; xin[tid + 256] *= r;
        __syncthreads();
    }
    const float* Wp = W + jb + jl;
    const int k0 = kp * 128;
    float a0 = 0.f, a1 = 0.f, a2 = 0.f, a3 = 0.f, a4 = 0.f, a5 = 0.f, a6 = 0.f, a7 = 0.f;
    for (int k = k0; k < k0 + 128; k += 8) {
        a0 += xin[k + 0] * Wp[(size_t)(k + 0) * D];
        a1 += xin[k + 1] * Wp[(size_t)(k + 1) * D];
        a2 += xin[k + 2] * Wp[(size_t)(k + 2) * D];
        a3 += xin[k + 3] * Wp[(size_t)(k + 3) * D];
        a4 += xin[k + 4] * Wp[(size_t)(k + 4) * D];
        a5 += xin[k + 5] * Wp[(size_t)(k + 5) * D];
        a6 += xin[k + 6] * Wp[(size_t)(k + 6) * D];
        a7 += xin[k + 7] * Wp[(size_t)(k + 7) * D];
    }
    part[kp][jl] = ((a0 + a1) + (a2 + a3)) + ((a4 + a5) + (a6 + a7));
    __syncthreads();
    if (tid < 64) {
        float s = part[0][tid] + part[1][tid] + part[2][tid] + part[3][tid] + bias[jb + tid];
        wout[b * D + jb + tid] = leaky(s);
    }
}

// ---------------- style + rstd for ALL layers, one dispatch ----------------
__global__ __launch_bounds__(256) void style_rstd_kernel(
    const float* __restrict__ Aw, const float* __restrict__ Ab,
    const float* __restrict__ convw)
{
    int l = blockIdx.x + 1;        // layers 1..8
    int b = blockIdx.y;
    int tid = threadIdx.x;
    __shared__ float ws_[D];
    __shared__ float part[2][CCH];
    __shared__ float st[CCH];
    ws_[tid] = g_w[0][b * D + tid];
    ws_[tid + 256] = g_w[0][b * D + tid + 256];
    __syncthreads();
    {
        int c = tid & 127, kh = tid >> 7;
        const float* Ap = Aw + (size_t)l * D * CCH + c;
        const int k0 = kh * 256;
        float a0 = 0.f, a1 = 0.f, a2 = 0.f, a3 = 0.f, a4 = 0.f, a5 = 0.f, a6 = 0.f, a7 = 0.f;
        for (int k = k0; k < k0 + 256; k += 8) {
            a0 += ws_[k + 0] * Ap[(size_t)(k + 0) * CCH];
            a1 += ws_[k + 1] * Ap[(size_t)(k + 1) * CCH];
            a2 += ws_[k + 2] * Ap[(size_t)(k + 2) * CCH];
            a3 += ws_[k + 3] * Ap[(size_t)(k + 3) * CCH];
            a4 += ws_[k + 4] * Ap[(size_t)(k + 4) * CCH];
            a5 += ws_[k + 5] * Ap[(size_t)(k + 5) * CCH];
            a6 += ws_[k + 6] * Ap[(size_t)(k + 6) * CCH];
            a7 += ws_[k + 7] * Ap[(size_t)(k + 7) * CCH];
        }
        part[kh][c] = ((a0 + a1) + (a2 + a3)) + ((a4 + a5) + (a6 + a7));
    }
    __syncthreads();
    if (tid < CCH) {
        float s = part[0][tid] + part[1][tid] + Ab[l * CCH + tid];
        st[tid] = s;
        g_style_all[((size_t)l * BS + b) * CCH + tid] = s;
    }
    __syncthreads();
    int colid = tid >> 4, kpart = tid & 15;
    for (int co8 = 0; co8 < 8; ++co8) {
        int cout = co8 * 16 + colid;
        const float* wp = convw + ((size_t)(l * CCH + cout) * CCH + kpart * 8) * 9;
        float wf[72];
#pragma unroll
        for (int q = 0; q < 18; ++q) {
            float4 t = *reinterpret_cast<const float4*>(wp + q * 4);
            wf[q * 4 + 0] = t.x; wf[q * 4 + 1] = t.y; wf[q * 4 + 2] = t.z; wf[q * 4 + 3] = t.w;
        }
        float s = 0.f;
#pragma unroll
        for (int ci = 0; ci < 8; ++ci) {
            float sv = st[kpart * 8 + ci];
#pragma unroll
            for (int k = 0; k < 9; ++k) { float m = wf[ci * 9 + k] * sv; s += m * m; }
        }
#pragma unroll
        for (int off = 8; off > 0; off >>= 1) s += __shfl_down(s, off, 16);
        if (kpart == 0) g_rstd_all[((size_t)l * BS + b) * CCH + cout] = rsqrtf(s + 1e-8f);
    }
}

// ---------------- MFMA modulated conv (NHWC bf16 in/out) ----------------
// Block: PF*16 px (row band) x ALL 128 co; 4 waves; wave owns 2 co-frags.
// UPM: 0 = plain staging; 1 = fused bilinear 2x upsample; 2 = fused layer-0+upsample.
template<int LW, int PF, int UPM>
__global__ __launch_bounds__(256) void conv_mfma_kernel(
    int srcSel, int layer, int layerNext,
    const float* __restrict__ noise,
    const float* __restrict__ Bw, const float* __restrict__ Bb,
    const float* __restrict__ noise0,
    const float* __restrict__ Bw0, const float* __restrict__ Bb0)
{
    constexpr int W = 1 << LW;
    constexpr int PX = PF * 16;
    constexpr int R = PX >> LW;
    constexpr int SW = W + 2;
    constexpr int ROWS = R + 2;
    constexpr int NS = W * W;
    constexpr int WIN = W / 2;          // source res for UPM 1/2

    const short* xin = srcSel ? g_bufB : g_bufA;
    short* xout = srcSel ? g_bufA : g_bufB;

    const int b = blockIdx.y;
    const int pixBase = blockIdx.x * PX;
    const int rowBase = pixBase >> LW;
    const int tid = threadIdx.x;
    const int lane = tid & 63;
    const int wave = tid >> 6;

    __shared__ short xs[ROWS * SW * CCH];
    __shared__ float style_s[CCH];
    constexpr int SMSZ = (UPM == 2) ? 16 * CCH : 1;
    __shared__ short sm[SMSZ];

    if (tid < CCH)
        style_s[tid] = layerNext ? g_style_all[((size_t)layerNext * BS + b) * CCH + tid] : 1.f;

    if (UPM == 2) {
        // layer-0 source tile: leaky(noise0*Bw0+Bb0) * style[1], 4x4 NHWC bf16
        for (int u = tid; u < 16 * CCH; u += 256) {
            int c = u & 127;
            int pp = u >> 7;
            float v = leaky(noise0[b * 4096 + pp] * Bw0[c] + Bb0[c])
                      * g_style_all[((size_t)1 * BS + b) * CCH + c];
            sm[u] = f2b(v);
        }
        __syncthreads();
    }

    // ---- stage x into swizzled LDS ----
    {
        const short* src = xin + (size_t)b * NS * CCH;          // UPM0
        const short* srcH = xin + (size_t)b * WIN * WIN * CCH;  // UPM1
        constexpr int UN = ROWS * SW * 16;
        for (int u = tid; u < UN; u += 256) {
            int ck = u & 15;
            int rem = u >> 4;
            int col = rem % SW;
            int rr = rem / SW;
            int gy = rowBase + rr - 1, gx = col - 1;
            short8 v = {0, 0, 0, 0, 0, 0, 0, 0};
            if (gy >= 0 && gy < W && gx >= 0 && gx < W) {
                if (UPM == 0) {
                    v = *reinterpret_cast<const short8*>(&src[((size_t)gy * W + gx) * CCH + ck * 8]);
                } else {
                    int y0, y1, x0, x1; float wy0, wy1, wx0, wx1;
                    uptaps(gy, WIN, y0, y1, wy0, wy1);
                    uptaps(gx, WIN, x0, x1, wx0, wx1);
                    const short* sp = (UPM == 2) ? sm : srcH;
                    short8 a00 = *reinterpret_cast<const short8*>(&sp[((size_t)y0 * WIN + x0) * CCH + ck * 8]);
                    short8 a01 = *reinterpret_cast<const short8*>(&sp[((size_t)y0 * WIN + x1) * CCH + ck * 8]);
                    short8 a10 = *reinterpret_cast<const short8*>(&sp[((size_t)y1 * WIN + x0) * CCH + ck * 8]);
                    short8 a11 = *reinterpret_cast<const short8*>(&sp[((size_t)y1 * WIN + x1) * CCH + ck * 8]);
                    float w00 = wy0 * wx0, w01 = wy0 * wx1, w10 = wy1 * wx0, w11 = wy1 * wx1;
#pragma unroll
                    for (int j = 0; j < 8; ++j)
                        v[j] = f2b(w00 * b2f(a00[j]) + w01 * b2f(a01[j])
                                 + w10 * b2f(a10[j]) + w11 * b2f(a11[j]));
                }
            }
            *reinterpret_cast<short8*>(&xs[(((rr * SW + col) * CCH) + ck * 8) ^ swz(col)]) = v;
        }
    }
    __syncthreads();

    int rL[PF], cL[PF];
#pragma unroll
    for (int pf = 0; pf < PF; ++pf) {
        int pl = pf * 16 + (lane & 15);
        cL[pf] = pl & (W - 1);
        rL[pf] = pl >> LW;
    }
    const int grpoff = (lane >> 4) * 8;

    f32x4 acc[2][PF] = {};
    const short* wl0 = g_wpack + ((size_t)layer * 9 * 4 * 8 * 64
                                  + (size_t)(wave * 2) * 64 + lane) * 8;
    const short* wl1 = wl0 + 64 * 8;

    short8 wc0 = *reinterpret_cast<const short8*>(wl0);
    short8 wc1 = *reinterpret_cast<const short8*>(wl1);
#pragma unroll
    for (int k = 0; k < 36; ++k) {
        short8 wn0 = wc0, wn1 = wc1;
        if (k + 1 < 36) {
            wn0 = *reinterpret_cast<const short8*>(wl0 + (size_t)(k + 1) * 4096);
            wn1 = *reinterpret_cast<const short8*>(wl1 + (size_t)(k + 1) * 4096);
        }
        const int tap = k >> 2, ch = k & 3;
        const int ky = tap / 3, kx = tap - ky * 3;
#pragma unroll
        for (int pf = 0; pf < PF; ++pf) {
            int col = cL[pf] + kx;
            int idx = (((rL[pf] + ky) * SW + col) * CCH + (ch << 5) + grpoff) ^ swz(col);
            short8 xf = *reinterpret_cast<const short8*>(&xs[idx]);
            acc[0][pf] = __builtin_amdgcn_mfma_f32_16x16x32_bf16(wc0, xf, acc[0][pf], 0, 0, 0);
            acc[1][pf] = __builtin_amdgcn_mfma_f32_16x16x32_bf16(wc1, xf, acc[1][pf], 0, 0, 0);
        }
        wc0 = wn0; wc1 = wn1;
    }

    // ---- epilogue: demod + noise + leaky, fold next style, bf16 NHWC short4 stores ----
    float nz[PF];
#pragma unroll
    for (int pf = 0; pf < PF; ++pf)
        nz[pf] = noise[b * 4096 + pixBase + pf * 16 + (lane & 15)];
#pragma unroll
    for (int cf = 0; cf < 2; ++cf) {
        const int coB = (wave * 2 + cf) * 16 + (lane >> 4) * 4;
        float rs[4], bw[4], bb[4], sn[4];
#pragma unroll
        for (int r = 0; r < 4; ++r) {
            rs[r] = g_rstd_all[((size_t)layer * BS + b) * CCH + coB + r];
            bw[r] = Bw[coB + r];
            bb[r] = Bb[coB + r];
            sn[r] = style_s[coB + r];
        }
#pragma unroll
        for (int pf = 0; pf < PF; ++pf) {
            int px = pixBase + pf * 16 + (lane & 15);
            short4v o;
#pragma unroll
            for (int r = 0; r < 4; ++r) {
                float v = leaky(acc[cf][pf][r] * rs[r] + nz[pf] * bw[r] + bb[r]) * sn[r];
                o[r] = f2b(v);
            }
            *reinterpret_cast<short4v*>(&xout[((size_t)b * NS + px) * CCH + coB]) = o;
        }
    }
}

// ---------------- MFMA toRGB (W=64; 3 real rows in 16-row M tile; waves split K) ----------------
__global__ __launch_bounds__(256) void rgb_mfma_kernel(
    int srcSel, const float* __restrict__ rgbb, float* __restrict__ out)
{
    constexpr int W = 64, SW = 66, ROWS = 3, NS = 4096;
    const short* xin = srcSel ? g_bufB : g_bufA;

    const int b = blockIdx.y;
    const int pixBase = blockIdx.x * 64;
    const int rowBase = pixBase >> 6;
    const int tid = threadIdx.x;
    const int lane = tid & 63;
    const int wave = tid >> 6;     // K-chunk

    __shared__ short xs[ROWS * SW * CCH];

    {
        const short* src = xin + (size_t)b * NS * CCH;
        constexpr int UN = ROWS * SW * 16;
        for (int u = tid; u < UN; u += 256) {
            int ck = u & 15;
            int rem = u >> 4;
            int col = rem % SW;
            int rr = rem / SW;
            int gy = rowBase + rr - 1, gx = col - 1;
            short8 v = {0, 0, 0, 0, 0, 0, 0, 0};
            if (gy >= 0 && gy < W && gx >= 0 && gx < W)
                v = *reinterpret_cast<const short8*>(&src[((size_t)gy * W + gx) * CCH + ck * 8]);
            *reinterpret_cast<short8*>(&xs[(((rr * SW + col) * CCH) + ck * 8) ^ swz(col)]) = v;
        }
    }
    __syncthreads();

    const int grpoff = (lane >> 4) * 8;
    const int cl = lane & 15;
    f32x4 acc[4] = {};
#pragma unroll
    for (int tap = 0; tap < 9; ++tap) {
        const int ky = tap / 3, kx = tap - ky * 3;
        short8 wf = *reinterpret_cast<const short8*>(
            &g_rgbpack[((size_t)(tap * 4 + wave) * 64 + lane) * 8]);
#pragma unroll
        for (int pf = 0; pf < 4; ++pf) {
            int col = cl + pf * 16 + kx;
            int idx = ((ky * SW + col) * CCH + (wave << 5) + grpoff) ^ swz(col);
            short8 xf = *reinterpret_cast<const short8*>(&xs[idx]);
            acc[pf] = __builtin_amdgcn_mfma_f32_16x16x32_bf16(wf, xf, acc[pf], 0, 0, 0);
        }
    }
    __syncthreads();
    float* red = reinterpret_cast<float*>(xs);   // reuse LDS for K-reduction
    if (wave > 0) {
#pragma unroll
        for (int pf = 0; pf < 4; ++pf)
#pragma unroll
            for (int r = 0; r < 4; ++r)
                red[(((wave - 1) * 4 + pf) * 64 + lane) * 4 + r] = acc[pf][r];
    }
    __syncthreads();
    if (wave == 0 && (lane >> 4) == 0) {
#pragma unroll
        for (int pf = 0; pf < 4; ++pf) {
            int px = pixBase + pf * 16 + cl;
#pragma unroll
            for (int r = 0; r < 3; ++r) {
                float s = acc[pf][r];
#pragma unroll
                for (int wv = 0; wv < 3; ++wv)
                    s += red[((wv * 4 + pf) * 64 + lane) * 4 + r];
                out[(size_t)(b * 3 + r) * NS + px] = s + rgbb[r];
            }
        }
    }
}

// ---------------- launch ----------------
extern "C" void kernel_launch(void* const* d_in, const int* in_sizes, int n_in,
                              void* d_out, int out_size, void* d_ws, size_t ws_size,
                              hipStream_t stream)
{
    const float* latent = (const float*)d_in[0];
    const float* noise  = (const float*)d_in[1];
    const float* map_w  = (const float*)d_in[2];
    const float* map_b  = (const float*)d_in[3];
    const float* A_w    = (const float*)d_in[4];
    const float* A_b    = (const float*)d_in[5];
    const float* B_w    = (const float*)d_in[6];
    const float* B_b    = (const float*)d_in[7];
    const float* conv_w = (const float*)d_in[8];
    const float* rgb_w  = (const float*)d_in[9];
    const float* rgb_b  = (const float*)d_in[10];
    float* out = (float*)d_out;
    (void)d_ws; (void)ws_size;

    wprep_kernel<<<(NLAYERS * 9 * 4 * 8 * 64 + 255) / 256, 256, 0, stream>>>(conv_w);
    rgbprep_kernel<<<(9 * 4 * 64 + 255) / 256, 256, 0, stream>>>(rgb_w);

    // mapping: 8 dispatches (layer-serial), pixelnorm fused into layer 0; ends in g_w[0]
    int wsel = 0;
    for (int i = 0; i < LMAP; ++i) {
        map_fc_kernel<<<dim3(8, BS), 256, 0, stream>>>(
            wsel, i == 0 ? 1 : 0, latent, map_w + (size_t)i * D * D, map_b + i * D);
        wsel ^= 1;
    }

    style_rstd_kernel<<<dim3(8, BS), 256, 0, stream>>>(A_w, A_b, conv_w);

    int cur = 1;   // pretend data in B so conv1 writes A
    int Hc = 4;
    for (int i = 1; i < NLAYERS; ++i) {
        if (i & 1) Hc *= 2;    // upsample fused into conv for odd i
        int ns = Hc * Hc;
        int lnext = (i < 8) ? (i + 1) : 0;
        const float* nz = noise + (size_t)i * BS * 4096;
        switch (i) {
            case 1: conv_mfma_kernel<3, 4, 2><<<dim3(ns / 64, BS), 256, 0, stream>>>(cur, i, lnext, nz, B_w + i * CCH, B_b + i * CCH, noise, B_w, B_b); break;
            case 2: conv_mfma_kernel<3, 4, 0><<<dim3(ns / 64, BS), 256, 0, stream>>>(cur, i, lnext, nz, B_w + i * CCH, B_b + i * CCH, noise, B_w, B_b); break;
            case 3: conv_mfma_kernel<4, 8, 1><<<dim3(ns / 128, BS), 256, 0, stream>>>(cur, i, lnext, nz, B_w + i * CCH, B_b + i * CCH, noise, B_w, B_b); break;
            case 4: conv_mfma_kernel<4, 8, 0><<<dim3(ns / 128, BS), 256, 0, stream>>>(cur, i, lnext, nz, B_w + i * CCH, B_b + i * CCH, noise, B_w, B_b); break;
            case 5: conv_mfma_kernel<5, 8, 1><<<dim3(ns / 128, BS), 256, 0, stream>>>(cur, i, lnext, nz, B_w + i * CCH, B_b + i * CCH, noise, B_w, B_b); break;
            case 6: conv_mfma_kernel<5, 8, 0><<<dim3(ns / 128, BS), 256, 0, stream>>>(cur, i, lnext, nz, B_w + i * CCH, B_b + i * CCH, noise, B_w, B_b); break;
            case 7: conv_mfma_kernel<6, 8, 1><<<dim3(ns / 128, BS), 256, 0, stream>>>(cur, i, lnext, nz, B_w + i * CCH, B_b + i * CCH, noise, B_w, B_b); break;
            case 8: conv_mfma_kernel<6, 8, 0><<<dim3(ns / 128, BS), 256, 0, stream>>>(cur, i, lnext, nz, B_w + i * CCH, B_b + i * CCH, noise, B_w, B_b); break;
        }
        cur ^= 1;
    }

    rgb_mfma_kernel<<<dim3(64, BS), 256, 0, stream>>>(cur, rgb_b, out);
}

// Round 10
// 229.325 us; speedup vs baseline: 1.3774x; 1.0721x over previous
//
#include <hip/hip_runtime.h>
#include <hip/hip_bf16.h>

#define BS 8
#define D 512
#define CCH 128
#define LMAP 8
#define NLAYERS 9

typedef short short8 __attribute__((ext_vector_type(8)));
typedef short short4v __attribute__((ext_vector_type(4)));
typedef float f32x4 __attribute__((ext_vector_type(4)));

// ---- module-global scratch ----
// activations: bf16 NHWC [b][px][ci]
__device__ short g_bufA[(size_t)BS * 4096 * CCH];   // 8.4 MB
__device__ short g_bufB[(size_t)BS * 4096 * CCH];   // 8.4 MB
__device__ float g_w[2][BS * D];
__device__ float g_style_all[NLAYERS * BS * CCH];
__device__ float g_rstd_all[NLAYERS * BS * CCH];
// packed bf16 weight fragments: [layer][tap][chunk4][cogrp8][lane64][8]
__device__ short g_wpack[(size_t)NLAYERS * 9 * 4 * 8 * 64 * 8];   // 2.65 MB
// rgb: [tap][chunk4][lane64][8] (M=16 rows, rows 0-2 real)
__device__ short g_rgbpack[9 * 4 * 64 * 8];

__device__ __forceinline__ float leaky(float v) { return v >= 0.f ? v : 0.2f * v; }
__device__ __forceinline__ short f2b(float f) {
    __hip_bfloat16 h = __float2bfloat16(f);
    return *reinterpret_cast<short*>(&h);
}
__device__ __forceinline__ float b2f(short s) {
    return __uint_as_float(((unsigned int)(unsigned short)s) << 16);
}
// bank swizzle on short-index bits 3..5 (keeps 8-short blocks intact)
__device__ __forceinline__ int swz(int col) { return ((col ^ (col >> 3)) & 7) << 3; }

// upsample tap params (jax half-pixel + boundary renorm), per axis
__device__ __forceinline__ void uptaps(int o, int Win, int& i0, int& i1, float& w0, float& w1)
{
    int m = o >> 1;
    if ((o & 1) == 0) { i0 = m - 1; i1 = m; w0 = 0.25f; w1 = 0.75f; if (i0 < 0) { i0 = 0; w0 = 0.f; w1 = 1.f; } }
    else              { i0 = m; i1 = m + 1; w0 = 0.75f; w1 = 0.25f; if (i1 >= Win) { i1 = Win - 1; w0 = 1.f; w1 = 0.f; } }
}

// ---------------- weight fragment prep ----------------
__global__ __launch_bounds__(256) void wprep_kernel(const float* __restrict__ convw)
{
    int idx = blockIdx.x * 256 + threadIdx.x;        // [layer][tap][chunk][cogrp][lane]
    if (idx >= NLAYERS * 9 * 4 * 8 * 64) return;
    int lane = idx & 63;
    int cogrp = (idx >> 6) & 7;
    int chunk = (idx >> 9) & 3;
    int t = idx >> 11;
    int layer = t / 9, tap = t - layer * 9;
    int co = cogrp * 16 + (lane & 15);
    int ci0 = chunk * 32 + (lane >> 4) * 8;
    short8 v;
#pragma unroll
    for (int j = 0; j < 8; ++j)
        v[j] = f2b(convw[(((size_t)layer * CCH + co) * CCH + ci0 + j) * 9 + tap]);
    *reinterpret_cast<short8*>(&g_wpack[(size_t)idx * 8]) = v;
}

__global__ void rgbprep_kernel(const float* __restrict__ rgbw)
{
    int idx = blockIdx.x * 256 + threadIdx.x;        // [tap][chunk][lane]
    if (idx >= 9 * 4 * 64) return;
    int lane = idx & 63;
    int chunk = (idx >> 6) & 3;
    int tap = idx >> 8;
    int co = lane & 15;
    int ci0 = chunk * 32 + (lane >> 4) * 8;
    short8 v;
#pragma unroll
    for (int j = 0; j < 8; ++j)
        v[j] = (co < 3) ? f2b(rgbw[((size_t)(co * CCH) + ci0 + j) * 9 + tap]) : (short)0;
    *reinterpret_cast<short8*>(&g_rgbpack[(size_t)idx * 8]) = v;
}

// ---------------- Mapping FC (64 blocks/layer, pixelnorm in layer 0, 8-deep ILP) ----------------
__global__ __launch_bounds__(256) void map_fc_kernel(
    int srcSel, int useZ, const float* __restrict__ z,
    const float* __restrict__ W, const float* __restrict__ bias)
{
    float* wout = g_w[srcSel ^ 1];
    int b = blockIdx.y;
    int jb = blockIdx.x * 64;
    int tid = threadIdx.x;
    int jl = tid & 63, kp = tid >> 6;
    __shared__ float xin[D];
    __shared__ float part[4][64];
    __shared__ float wred[4];
    if (useZ) {
        xin[tid] = z[b * D + tid];
        xin[tid + 256] = z[b * D + tid + 256];
    } else {
        const float* win = g_w[srcSel];
        xin[tid] = win[b * D + tid];
        xin[tid + 256] = win[b * D + tid + 256];
    }
    __syncthreads();
    if (useZ) {
        float p = xin[tid] * xin[tid] + xin[tid + 256] * xin[tid + 256];
#pragma unroll
        for (int off = 32; off > 0; off >>= 1) p += __shfl_down(p, off, 64);
        if ((tid & 63) == 0) wred[tid >> 6] = p;
        __syncthreads();
        float ss = wred[0] + wred[1] + wred[2] + wred[3];
        float r = rsqrtf(ss * (1.f / 512.f) + 1e-8f);
        xin[tid] *= r; xin[tid + 256] *= r;
        __syncthreads();
    }
    const float* Wp = W + jb + jl;
    const int k0 = kp * 128;
    float a0 = 0.f, a1 = 0.f, a2 = 0.f, a3 = 0.f, a4 = 0.f, a5 = 0.f, a6 = 0.f, a7 = 0.f;
    for (int k = k0; k < k0 + 128; k += 8) {
        a0 += xin[k + 0] * Wp[(size_t)(k + 0) * D];
        a1 += xin[k + 1] * Wp[(size_t)(k + 1) * D];
        a2 += xin[k + 2] * Wp[(size_t)(k + 2) * D];
        a3 += xin[k + 3] * Wp[(size_t)(k + 3) * D];
        a4 += xin[k + 4] * Wp[(size_t)(k + 4) * D];
        a5 += xin[k + 5] * Wp[(size_t)(k + 5) * D];
        a6 += xin[k + 6] * Wp[(size_t)(k + 6) * D];
        a7 += xin[k + 7] * Wp[(size_t)(k + 7) * D];
    }
    part[kp][jl] = ((a0 + a1) + (a2 + a3)) + ((a4 + a5) + (a6 + a7));
    __syncthreads();
    if (tid < 64) {
        float s = part[0][tid] + part[1][tid] + part[2][tid] + part[3][tid] + bias[jb + tid];
        wout[b * D + jb + tid] = leaky(s);
    }
}

// ---------------- style + rstd for ALL layers, one dispatch ----------------
__global__ __launch_bounds__(256) void style_rstd_kernel(
    const float* __restrict__ Aw, const float* __restrict__ Ab,
    const float* __restrict__ convw)
{
    int l = blockIdx.x + 1;        // layers 1..8
    int b = blockIdx.y;
    int tid = threadIdx.x;
    __shared__ float ws_[D];
    __shared__ float part[2][CCH];
    __shared__ float st[CCH];
    ws_[tid] = g_w[0][b * D + tid];
    ws_[tid + 256] = g_w[0][b * D + tid + 256];
    __syncthreads();
    {
        int c = tid & 127, kh = tid >> 7;
        const float* Ap = Aw + (size_t)l * D * CCH + c;
        const int k0 = kh * 256;
        float a0 = 0.f, a1 = 0.f, a2 = 0.f, a3 = 0.f, a4 = 0.f, a5 = 0.f, a6 = 0.f, a7 = 0.f;
        for (int k = k0; k < k0 + 256; k += 8) {
            a0 += ws_[k + 0] * Ap[(size_t)(k + 0) * CCH];
            a1 += ws_[k + 1] * Ap[(size_t)(k + 1) * CCH];
            a2 += ws_[k + 2] * Ap[(size_t)(k + 2) * CCH];
            a3 += ws_[k + 3] * Ap[(size_t)(k + 3) * CCH];
            a4 += ws_[k + 4] * Ap[(size_t)(k + 4) * CCH];
            a5 += ws_[k + 5] * Ap[(size_t)(k + 5) * CCH];
            a6 += ws_[k + 6] * Ap[(size_t)(k + 6) * CCH];
            a7 += ws_[k + 7] * Ap[(size_t)(k + 7) * CCH];
        }
        part[kh][c] = ((a0 + a1) + (a2 + a3)) + ((a4 + a5) + (a6 + a7));
    }
    __syncthreads();
    if (tid < CCH) {
        float s = part[0][tid] + part[1][tid] + Ab[l * CCH + tid];
        st[tid] = s;
        g_style_all[((size_t)l * BS + b) * CCH + tid] = s;
    }
    __syncthreads();
    int colid = tid >> 4, kpart = tid & 15;
    for (int co8 = 0; co8 < 8; ++co8) {
        int cout = co8 * 16 + colid;
        const float* wp = convw + ((size_t)(l * CCH + cout) * CCH + kpart * 8) * 9;
        float wf[72];
#pragma unroll
        for (int q = 0; q < 18; ++q) {
            float4 t = *reinterpret_cast<const float4*>(wp + q * 4);
            wf[q * 4 + 0] = t.x; wf[q * 4 + 1] = t.y; wf[q * 4 + 2] = t.z; wf[q * 4 + 3] = t.w;
        }
        float s = 0.f;
#pragma unroll
        for (int ci = 0; ci < 8; ++ci) {
            float sv = st[kpart * 8 + ci];
#pragma unroll
            for (int k = 0; k < 9; ++k) { float m = wf[ci * 9 + k] * sv; s += m * m; }
        }
#pragma unroll
        for (int off = 8; off > 0; off >>= 1) s += __shfl_down(s, off, 16);
        if (kpart == 0) g_rstd_all[((size_t)l * BS + b) * CCH + cout] = rsqrtf(s + 1e-8f);
    }
}

// ---------------- MFMA modulated conv (NHWC bf16 in/out) ----------------
// Block: 64 px (row band) x 128 co; 4 waves = 2 px-halves x 2 co-halves.
// Each wave: 2 px-frags x 4 co-frags -> each ds_read feeds 4 MFMAs (MFMA-bound K-loop).
// UPM: 0 = plain staging; 1 = fused bilinear 2x upsample; 2 = fused layer-0+upsample.
template<int LW, int UPM>
__global__ __launch_bounds__(256) void conv_mfma_kernel(
    int srcSel, int layer, int layerNext,
    const float* __restrict__ noise,
    const float* __restrict__ Bw, const float* __restrict__ Bb,
    const float* __restrict__ noise0,
    const float* __restrict__ Bw0, const float* __restrict__ Bb0)
{
    constexpr int W = 1 << LW;
    constexpr int R = 64 >> LW;
    constexpr int SW = W + 2;
    constexpr int ROWS = R + 2;
    constexpr int NS = W * W;
    constexpr int WIN = W / 2;          // source res for UPM 1/2

    const short* xin = srcSel ? g_bufB : g_bufA;
    short* xout = srcSel ? g_bufA : g_bufB;

    const int b = blockIdx.y;
    const int pixBase = blockIdx.x * 64;
    const int rowBase = pixBase >> LW;
    const int tid = threadIdx.x;
    const int lane = tid & 63;
    const int wave = tid >> 6;
    const int wpx = wave & 1;      // pixel half: frags wpx*2 + {0,1}
    const int wco = wave >> 1;     // co half:   frags wco*4 + {0..3}

    __shared__ short xs[ROWS * SW * CCH];
    __shared__ float style_s[CCH];
    constexpr int SMSZ = (UPM == 2) ? 16 * CCH : 1;
    __shared__ short sm[SMSZ];

    if (tid < CCH)
        style_s[tid] = layerNext ? g_style_all[((size_t)layerNext * BS + b) * CCH + tid] : 1.f;

    if (UPM == 2) {
        // layer-0 source tile: leaky(noise0*Bw0+Bb0) * style[1], 4x4 NHWC bf16
        for (int u = tid; u < 16 * CCH; u += 256) {
            int c = u & 127;
            int pp = u >> 7;
            float v = leaky(noise0[b * 4096 + pp] * Bw0[c] + Bb0[c])
                      * g_style_all[((size_t)1 * BS + b) * CCH + c];
            sm[u] = f2b(v);
        }
        __syncthreads();
    }

    // ---- stage x into swizzled LDS ----
    {
        const short* src = xin + (size_t)b * NS * CCH;          // UPM0
        const short* srcH = xin + (size_t)b * WIN * WIN * CCH;  // UPM1
        constexpr int UN = ROWS * SW * 16;
        for (int u = tid; u < UN; u += 256) {
            int ck = u & 15;
            int rem = u >> 4;
            int col = rem % SW;
            int rr = rem / SW;
            int gy = rowBase + rr - 1, gx = col - 1;
            short8 v = {0, 0, 0, 0, 0, 0, 0, 0};
            if (gy >= 0 && gy < W && gx >= 0 && gx < W) {
                if (UPM == 0) {
                    v = *reinterpret_cast<const short8*>(&src[((size_t)gy * W + gx) * CCH + ck * 8]);
                } else {
                    int y0, y1, x0, x1; float wy0, wy1, wx0, wx1;
                    uptaps(gy, WIN, y0, y1, wy0, wy1);
                    uptaps(gx, WIN, x0, x1, wx0, wx1);
                    const short* sp = (UPM == 2) ? sm : srcH;
                    short8 a00 = *reinterpret_cast<const short8*>(&sp[((size_t)y0 * WIN + x0) * CCH + ck * 8]);
                    short8 a01 = *reinterpret_cast<const short8*>(&sp[((size_t)y0 * WIN + x1) * CCH + ck * 8]);
                    short8 a10 = *reinterpret_cast<const short8*>(&sp[((size_t)y1 * WIN + x0) * CCH + ck * 8]);
                    short8 a11 = *reinterpret_cast<const short8*>(&sp[((size_t)y1 * WIN + x1) * CCH + ck * 8]);
                    float w00 = wy0 * wx0, w01 = wy0 * wx1, w10 = wy1 * wx0, w11 = wy1 * wx1;
#pragma unroll
                    for (int j = 0; j < 8; ++j)
                        v[j] = f2b(w00 * b2f(a00[j]) + w01 * b2f(a01[j])
                                 + w10 * b2f(a10[j]) + w11 * b2f(a11[j]));
                }
            }
            *reinterpret_cast<short8*>(&xs[(((rr * SW + col) * CCH) + ck * 8) ^ swz(col)]) = v;
        }
    }
    __syncthreads();

    int rL[2], cL[2];
#pragma unroll
    for (int pf = 0; pf < 2; ++pf) {
        int pl = (wpx * 2 + pf) * 16 + (lane & 15);
        cL[pf] = pl & (W - 1);
        rL[pf] = pl >> LW;
    }
    const int grpoff = (lane >> 4) * 8;

    f32x4 acc[2][4] = {};   // [pf][cf]
    const short* wl = g_wpack + ((size_t)layer * 9 * 4 * 8 * 64
                                 + (size_t)(wco * 4) * 64 + lane) * 8;
    // co-frag streams at wl + cf*512; k-stride 4096 shorts

    short8 wc0 = *reinterpret_cast<const short8*>(wl);
    short8 wc1 = *reinterpret_cast<const short8*>(wl + 512);
    short8 wc2 = *reinterpret_cast<const short8*>(wl + 1024);
    short8 wc3 = *reinterpret_cast<const short8*>(wl + 1536);
#pragma unroll
    for (int k = 0; k < 36; ++k) {
        short8 wn0 = wc0, wn1 = wc1, wn2 = wc2, wn3 = wc3;
        if (k + 1 < 36) {
            const short* wk = wl + (size_t)(k + 1) * 4096;
            wn0 = *reinterpret_cast<const short8*>(wk);
            wn1 = *reinterpret_cast<const short8*>(wk + 512);
            wn2 = *reinterpret_cast<const short8*>(wk + 1024);
            wn3 = *reinterpret_cast<const short8*>(wk + 1536);
        }
        const int tap = k >> 2, ch = k & 3;
        const int ky = tap / 3, kx = tap - ky * 3;
#pragma unroll
        for (int pf = 0; pf < 2; ++pf) {
            int col = cL[pf] + kx;
            int idx = (((rL[pf] + ky) * SW + col) * CCH + (ch << 5) + grpoff) ^ swz(col);
            short8 xf = *reinterpret_cast<const short8*>(&xs[idx]);
            acc[pf][0] = __builtin_amdgcn_mfma_f32_16x16x32_bf16(wc0, xf, acc[pf][0], 0, 0, 0);
            acc[pf][1] = __builtin_amdgcn_mfma_f32_16x16x32_bf16(wc1, xf, acc[pf][1], 0, 0, 0);
            acc[pf][2] = __builtin_amdgcn_mfma_f32_16x16x32_bf16(wc2, xf, acc[pf][2], 0, 0, 0);
            acc[pf][3] = __builtin_amdgcn_mfma_f32_16x16x32_bf16(wc3, xf, acc[pf][3], 0, 0, 0);
        }
        wc0 = wn0; wc1 = wn1; wc2 = wn2; wc3 = wn3;
    }

    // ---- epilogue: demod + noise + leaky, fold next style, bf16 NHWC short4 stores ----
    float nz[2];
#pragma unroll
    for (int pf = 0; pf < 2; ++pf)
        nz[pf] = noise[b * 4096 + pixBase + (wpx * 2 + pf) * 16 + (lane & 15)];
#pragma unroll
    for (int cf = 0; cf < 4; ++cf) {
        const int coB = (wco * 4 + cf) * 16 + (lane >> 4) * 4;
        float rs[4], bw[4], bb[4], sn[4];
#pragma unroll
        for (int r = 0; r < 4; ++r) {
            rs[r] = g_rstd_all[((size_t)layer * BS + b) * CCH + coB + r];
            bw[r] = Bw[coB + r];
            bb[r] = Bb[coB + r];
            sn[r] = style_s[coB + r];
        }
#pragma unroll
        for (int pf = 0; pf < 2; ++pf) {
            int px = pixBase + (wpx * 2 + pf) * 16 + (lane & 15);
            short4v o;
#pragma unroll
            for (int r = 0; r < 4; ++r) {
                float v = leaky(acc[pf][cf][r] * rs[r] + nz[pf] * bw[r] + bb[r]) * sn[r];
                o[r] = f2b(v);
            }
            *reinterpret_cast<short4v*>(&xout[((size_t)b * NS + px) * CCH + coB]) = o;
        }
    }
}

// ---------------- MFMA toRGB (W=64; 3 real rows in 16-row M tile; waves split K) ----------------
__global__ __launch_bounds__(256) void rgb_mfma_kernel(
    int srcSel, const float* __restrict__ rgbb, float* __restrict__ out)
{
    constexpr int W = 64, SW = 66, ROWS = 3, NS = 4096;
    const short* xin = srcSel ? g_bufB : g_bufA;

    const int b = blockIdx.y;
    const int pixBase = blockIdx.x * 64;
    const int rowBase = pixBase >> 6;
    const int tid = threadIdx.x;
    const int lane = tid & 63;
    const int wave = tid >> 6;     // K-chunk

    __shared__ short xs[ROWS * SW * CCH];

    {
        const short* src = xin + (size_t)b * NS * CCH;
        constexpr int UN = ROWS * SW * 16;
        for (int u = tid; u < UN; u += 256) {
            int ck = u & 15;
            int rem = u >> 4;
            int col = rem % SW;
            int rr = rem / SW;
            int gy = rowBase + rr - 1, gx = col - 1;
            short8 v = {0, 0, 0, 0, 0, 0, 0, 0};
            if (gy >= 0 && gy < W && gx >= 0 && gx < W)
                v = *reinterpret_cast<const short8*>(&src[((size_t)gy * W + gx) * CCH + ck * 8]);
            *reinterpret_cast<short8*>(&xs[(((rr * SW + col) * CCH) + ck * 8) ^ swz(col)]) = v;
        }
    }
    __syncthreads();

    const int grpoff = (lane >> 4) * 8;
    const int cl = lane & 15;
    f32x4 acc[4] = {};
#pragma unroll
    for (int tap = 0; tap < 9; ++tap) {
        const int ky = tap / 3, kx = tap - ky * 3;
        short8 wf = *reinterpret_cast<const short8*>(
            &g_rgbpack[((size_t)(tap * 4 + wave) * 64 + lane) * 8]);
#pragma unroll
        for (int pf = 0; pf < 4; ++pf) {
            int col = cl + pf * 16 + kx;
            int idx = ((ky * SW + col) * CCH + (wave << 5) + grpoff) ^ swz(col);
            short8 xf = *reinterpret_cast<const short8*>(&xs[idx]);
            acc[pf] = __builtin_amdgcn_mfma_f32_16x16x32_bf16(wf, xf, acc[pf], 0, 0, 0);
        }
    }
    __syncthreads();
    float* red = reinterpret_cast<float*>(xs);   // reuse LDS for K-reduction
    if (wave > 0) {
#pragma unroll
        for (int pf = 0; pf < 4; ++pf)
#pragma unroll
            for (int r = 0; r < 4; ++r)
                red[(((wave - 1) * 4 + pf) * 64 + lane) * 4 + r] = acc[pf][r];
    }
    __syncthreads();
    if (wave == 0 && (lane >> 4) == 0) {
#pragma unroll
        for (int pf = 0; pf < 4; ++pf) {
            int px = pixBase + pf * 16 + cl;
#pragma unroll
            for (int r = 0; r < 3; ++r) {
                float s = acc[pf][r];
#pragma unroll
                for (int wv = 0; wv < 3; ++wv)
                    s += red[((wv * 4 + pf) * 64 + lane) * 4 + r];
                out[(size_t)(b * 3 + r) * NS + px] = s + rgbb[r];
            }
        }
    }
}

// ---------------- launch ----------------
extern "C" void kernel_launch(void* const* d_in, const int* in_sizes, int n_in,
                              void* d_out, int out_size, void* d_ws, size_t ws_size,
                              hipStream_t stream)
{
    const float* latent = (const float*)d_in[0];
    const float* noise  = (const float*)d_in[1];
    const float* map_w  = (const float*)d_in[2];
    const float* map_b  = (const float*)d_in[3];
    const float* A_w    = (const float*)d_in[4];
    const float* A_b    = (const float*)d_in[5];
    const float* B_w    = (const float*)d_in[6];
    const float* B_b    = (const float*)d_in[7];
    const float* conv_w = (const float*)d_in[8];
    const float* rgb_w  = (const float*)d_in[9];
    const float* rgb_b  = (const float*)d_in[10];
    float* out = (float*)d_out;
    (void)d_ws; (void)ws_size;

    wprep_kernel<<<(NLAYERS * 9 * 4 * 8 * 64 + 255) / 256, 256, 0, stream>>>(conv_w);
    rgbprep_kernel<<<(9 * 4 * 64 + 255) / 256, 256, 0, stream>>>(rgb_w);

    // mapping: 8 dispatches (layer-serial), pixelnorm fused into layer 0; ends in g_w[0]
    int wsel = 0;
    for (int i = 0; i < LMAP; ++i) {
        map_fc_kernel<<<dim3(8, BS), 256, 0, stream>>>(
            wsel, i == 0 ? 1 : 0, latent, map_w + (size_t)i * D * D, map_b + i * D);
        wsel ^= 1;
    }

    style_rstd_kernel<<<dim3(8, BS), 256, 0, stream>>>(A_w, A_b, conv_w);

    int cur = 1;   // pretend data in B so conv1 writes A
    int Hc = 4;
    for (int i = 1; i < NLAYERS; ++i) {
        if (i & 1) Hc *= 2;    // upsample fused into conv for odd i
        int ns = Hc * Hc;
        int lnext = (i < 8) ? (i + 1) : 0;
        dim3 grid(ns / 64, BS);
        const float* nz = noise + (size_t)i * BS * 4096;
        switch (i) {
            case 1: conv_mfma_kernel<3, 2><<<grid, 256, 0, stream>>>(cur, i, lnext, nz, B_w + i * CCH, B_b + i * CCH, noise, B_w, B_b); break;
            case 2: conv_mfma_kernel<3, 0><<<grid, 256, 0, stream>>>(cur, i, lnext, nz, B_w + i * CCH, B_b + i * CCH, noise, B_w, B_b); break;
            case 3: conv_mfma_kernel<4, 1><<<grid, 256, 0, stream>>>(cur, i, lnext, nz, B_w + i * CCH, B_b + i * CCH, noise, B_w, B_b); break;
            case 4: conv_mfma_kernel<4, 0><<<grid, 256, 0, stream>>>(cur, i, lnext, nz, B_w + i * CCH, B_b + i * CCH, noise, B_w, B_b); break;
            case 5: conv_mfma_kernel<5, 1><<<grid, 256, 0, stream>>>(cur, i, lnext, nz, B_w + i * CCH, B_b + i * CCH, noise, B_w, B_b); break;
            case 6: conv_mfma_kernel<5, 0><<<grid, 256, 0, stream>>>(cur, i, lnext, nz, B_w + i * CCH, B_b + i * CCH, noise, B_w, B_b); break;
            case 7: conv_mfma_kernel<6, 1><<<grid, 256, 0, stream>>>(cur, i, lnext, nz, B_w + i * CCH, B_b + i * CCH, noise, B_w, B_b); break;
            case 8: conv_mfma_kernel<6, 0><<<grid, 256, 0, stream>>>(cur, i, lnext, nz, B_w + i * CCH, B_b + i * CCH, noise, B_w, B_b); break;
        }
        cur ^= 1;
    }

    rgb_mfma_kernel<<<dim3(64, BS), 256, 0, stream>>>(cur, rgb_b, out);
}

// Round 11
// 211.224 us; speedup vs baseline: 1.4955x; 1.0857x over previous
//
#include <hip/hip_runtime.h>
#include <hip/hip_bf16.h>

#define BS 8
#define D 512
#define CCH 128
#define LMAP 8
#define NLAYERS 9

typedef short short8 __attribute__((ext_vector_type(8)));
typedef short short4v __attribute__((ext_vector_type(4)));
typedef float f32x4 __attribute__((ext_vector_type(4)));

// ---- module-global scratch ----
__device__ short g_bufA[(size_t)BS * 4096 * CCH];   // bf16 NHWC [b][px][ci]
__device__ short g_bufB[(size_t)BS * 4096 * CCH];
__device__ float g_w[2][BS * D];
__device__ float g_style_all[NLAYERS * BS * CCH];
__device__ float g_rstd_all[NLAYERS * BS * CCH];
__device__ float g_s2[(size_t)NLAYERS * CCH * CCH];              // S2[l][co][ci] = sum_tap w^2
__device__ short g_wpack[(size_t)NLAYERS * 9 * 4 * 8 * 64 * 8];  // packed bf16 W-frags
__device__ short g_rgbpack[9 * 4 * 64 * 8];

__device__ __forceinline__ float leaky(float v) { return v >= 0.f ? v : 0.2f * v; }
__device__ __forceinline__ short f2b(float f) {
    __hip_bfloat16 h = __float2bfloat16(f);
    return *reinterpret_cast<short*>(&h);
}
__device__ __forceinline__ float b2f(short s) {
    return __uint_as_float(((unsigned int)(unsigned short)s) << 16);
}
__device__ __forceinline__ int swz(int col) { return ((col ^ (col >> 3)) & 7) << 3; }

__device__ __forceinline__ void uptaps(int o, int Win, int& i0, int& i1, float& w0, float& w1)
{
    int m = o >> 1;
    if ((o & 1) == 0) { i0 = m - 1; i1 = m; w0 = 0.25f; w1 = 0.75f; if (i0 < 0) { i0 = 0; w0 = 0.f; w1 = 1.f; } }
    else              { i0 = m; i1 = m + 1; w0 = 0.75f; w1 = 0.25f; if (i1 >= Win) { i1 = Win - 1; w0 = 1.f; w1 = 0.f; } }
}

// ---------------- fused prep: wpack + rgbpack + S2 ----------------
#define WPN (NLAYERS * 9 * 4 * 8 * 64)
#define RGBN (9 * 4 * 64)
#define S2N (NLAYERS * CCH * CCH)
__global__ __launch_bounds__(256) void prep_kernel(
    const float* __restrict__ convw, const float* __restrict__ rgbw)
{
    int idx = blockIdx.x * 256 + threadIdx.x;
    if (idx < WPN) {
        int lane = idx & 63;
        int cogrp = (idx >> 6) & 7;
        int chunk = (idx >> 9) & 3;
        int t = idx >> 11;
        int layer = t / 9, tap = t - layer * 9;
        int co = cogrp * 16 + (lane & 15);
        int ci0 = chunk * 32 + (lane >> 4) * 8;
        short8 v;
#pragma unroll
        for (int j = 0; j < 8; ++j)
            v[j] = f2b(convw[(((size_t)layer * CCH + co) * CCH + ci0 + j) * 9 + tap]);
        *reinterpret_cast<short8*>(&g_wpack[(size_t)idx * 8]) = v;
    } else if (idx < WPN + RGBN) {
        int u = idx - WPN;
        int lane = u & 63;
        int chunk = (u >> 6) & 3;
        int tap = u >> 8;
        int co = lane & 15;
        int ci0 = chunk * 32 + (lane >> 4) * 8;
        short8 v;
#pragma unroll
        for (int j = 0; j < 8; ++j)
            v[j] = (co < 3) ? f2b(rgbw[((size_t)(co * CCH) + ci0 + j) * 9 + tap]) : (short)0;
        *reinterpret_cast<short8*>(&g_rgbpack[(size_t)u * 8]) = v;
    } else if (idx < WPN + RGBN + S2N) {
        int u = idx - WPN - RGBN;         // [l][co][ci]
        const float* wp = convw + (size_t)u * 9;
        float s = 0.f;
#pragma unroll
        for (int t = 0; t < 9; ++t) { float m = wp[t]; s += m * m; }
        g_s2[u] = s;
    }
}

// ---------------- Mapping FC (64 blocks/layer, pixelnorm in layer 0, 16-deep ILP) ----------------
__global__ __launch_bounds__(256) void map_fc_kernel(
    int srcSel, int useZ, const float* __restrict__ z,
    const float* __restrict__ W, const float* __restrict__ bias)
{
    float* wout = g_w[srcSel ^ 1];
    int b = blockIdx.y;
    int jb = blockIdx.x * 64;
    int tid = threadIdx.x;
    int jl = tid & 63, kp = tid >> 6;
    __shared__ float xin[D];
    __shared__ float part[4][64];
    __shared__ float wred[4];
    if (useZ) {
        xin[tid] = z[b * D + tid];
        xin[tid + 256] = z[b * D + tid + 256];
    } else {
        const float* win = g_w[srcSel];
        xin[tid] = win[b * D + tid];
        xin[tid + 256] = win[b * D + tid + 256];
    }
    __syncthreads();
    if (useZ) {
        float p = xin[tid] * xin[tid] + xin[tid + 256] * xin[tid + 256];
#pragma unroll
        for (int off = 32; off > 0; off >>= 1) p += __shfl_down(p, off, 64);
        if ((tid & 63) == 0) wred[tid >> 6] = p;
        __syncthreads();
        float ss = wred[0] + wred[1] + wred[2] + wred[3];
        float r = rsqrtf(ss * (1.f / 512.f) + 1e-8f);
        xin[tid] *= r; xin[tid + 256] *= r;
        __syncthreads();
    }
    const float* Wp = W + jb + jl;
    const int k0 = kp * 128;
    float a[16];
#pragma unroll
    for (int j = 0; j < 16; ++j) a[j] = 0.f;
    for (int k = k0; k < k0 + 128; k += 16) {
#pragma unroll
        for (int j = 0; j < 16; ++j)
            a[j] += xin[k + j] * Wp[(size_t)(k + j) * D];
    }
    float s8 = 0.f;
#pragma unroll
    for (int j = 0; j < 16; ++j) s8 += a[j];
    part[kp][jl] = s8;
    __syncthreads();
    if (tid < 64) {
        float s = part[0][tid] + part[1][tid] + part[2][tid] + part[3][tid] + bias[jb + tid];
        wout[b * D + jb + tid] = leaky(s);
    }
}

// ---------------- style + rstd for ALL layers (rstd via S2), one dispatch ----------------
__global__ __launch_bounds__(256) void style_rstd_kernel(
    const float* __restrict__ Aw, const float* __restrict__ Ab)
{
    int l = blockIdx.x + 1;        // layers 1..8
    int b = blockIdx.y;
    int tid = threadIdx.x;
    __shared__ float ws_[D];
    __shared__ float part[2][CCH];
    __shared__ float st[CCH];
    ws_[tid] = g_w[0][b * D + tid];
    ws_[tid + 256] = g_w[0][b * D + tid + 256];
    __syncthreads();
    {
        int c = tid & 127, kh = tid >> 7;
        const float* Ap = Aw + (size_t)l * D * CCH + c;
        const int k0 = kh * 256;
        float a0 = 0.f, a1 = 0.f, a2 = 0.f, a3 = 0.f, a4 = 0.f, a5 = 0.f, a6 = 0.f, a7 = 0.f;
        for (int k = k0; k < k0 + 256; k += 8) {
            a0 += ws_[k + 0] * Ap[(size_t)(k + 0) * CCH];
            a1 += ws_[k + 1] * Ap[(size_t)(k + 1) * CCH];
            a2 += ws_[k + 2] * Ap[(size_t)(k + 2) * CCH];
            a3 += ws_[k + 3] * Ap[(size_t)(k + 3) * CCH];
            a4 += ws_[k + 4] * Ap[(size_t)(k + 4) * CCH];
            a5 += ws_[k + 5] * Ap[(size_t)(k + 5) * CCH];
            a6 += ws_[k + 6] * Ap[(size_t)(k + 6) * CCH];
            a7 += ws_[k + 7] * Ap[(size_t)(k + 7) * CCH];
        }
        part[kh][c] = ((a0 + a1) + (a2 + a3)) + ((a4 + a5) + (a6 + a7));
    }
    __syncthreads();
    if (tid < CCH) {
        float s = part[0][tid] + part[1][tid] + Ab[l * CCH + tid];
        st[tid] = s;
        g_style_all[((size_t)l * BS + b) * CCH + tid] = s;
    }
    __syncthreads();
    int colid = tid >> 4, kpart = tid & 15;
#pragma unroll
    for (int co8 = 0; co8 < 8; ++co8) {
        int cout = co8 * 16 + colid;
        const float* sp = g_s2 + ((size_t)l * CCH + cout) * CCH + kpart * 8;
        float s = 0.f;
#pragma unroll
        for (int j = 0; j < 8; ++j) { float sv = st[kpart * 8 + j]; s += sv * sv * sp[j]; }
#pragma unroll
        for (int off = 8; off > 0; off >>= 1) s += __shfl_down(s, off, 16);
        if (kpart == 0) g_rstd_all[((size_t)l * BS + b) * CCH + cout] = rsqrtf(s + 1e-8f);
    }
}

// ---------------- fused conv layers 1+2 (both 8x8), one block per batch ----------------
// Phase A: layer-0 minitile (from noise) -> bilinear up -> xs1 -> conv1 -> xs2 (LDS, swizzled).
// Phase B: conv2 from xs2 -> global (g_bufA), style[3] folded.
__global__ __launch_bounds__(256) void conv8_pair_kernel(
    const float* __restrict__ noise,
    const float* __restrict__ Bw, const float* __restrict__ Bb)
{
    constexpr int W = 8, SW = 10, ROWS = 10, NS = 64, WIN = 4;
    const int b = blockIdx.x;
    const int tid = threadIdx.x;
    const int lane = tid & 63;
    const int wave = tid >> 6;
    const int wpx = wave & 1;
    const int wco = wave >> 1;

    __shared__ short xs1[ROWS * SW * CCH];
    __shared__ short xs2[ROWS * SW * CCH];
    __shared__ short sm[16 * CCH];
    __shared__ float style2_s[CCH], style3_s[CCH];

    if (tid < CCH) {
        style2_s[tid] = g_style_all[((size_t)2 * BS + b) * CCH + tid];
        style3_s[tid] = g_style_all[((size_t)3 * BS + b) * CCH + tid];
    }
    // layer-0 source tile: leaky(noise0*Bw0+Bb0) * style[1], 4x4 NHWC bf16
    for (int u = tid; u < 16 * CCH; u += 256) {
        int c = u & 127;
        int pp = u >> 7;
        float v = leaky(noise[b * 4096 + pp] * Bw[c] + Bb[c])
                  * g_style_all[((size_t)1 * BS + b) * CCH + c];
        sm[u] = f2b(v);
    }
    // zero xs2 borders (rows 0,9 / cols 0,9)
    for (int u = tid; u < ROWS * SW * 16; u += 256) {
        int ck = u & 15;
        int cell = u >> 4;
        int col = cell % SW;
        int rr = cell / SW;
        if (rr >= 1 && rr <= 8 && col >= 1 && col <= 8) continue;
        short8 z = {0, 0, 0, 0, 0, 0, 0, 0};
        *reinterpret_cast<short8*>(&xs2[(((rr * SW + col) * CCH) + ck * 8) ^ swz(col)]) = z;
    }
    __syncthreads();

    // stage xs1 = bilinear-up(sm) with zero halo
    for (int u = tid; u < ROWS * SW * 16; u += 256) {
        int ck = u & 15;
        int rem = u >> 4;
        int col = rem % SW;
        int rr = rem / SW;
        int gy = rr - 1, gx = col - 1;
        short8 v = {0, 0, 0, 0, 0, 0, 0, 0};
        if (gy >= 0 && gy < W && gx >= 0 && gx < W) {
            int y0, y1, x0, x1; float wy0, wy1, wx0, wx1;
            uptaps(gy, WIN, y0, y1, wy0, wy1);
            uptaps(gx, WIN, x0, x1, wx0, wx1);
            short8 a00 = *reinterpret_cast<const short8*>(&sm[((size_t)y0 * WIN + x0) * CCH + ck * 8]);
            short8 a01 = *reinterpret_cast<const short8*>(&sm[((size_t)y0 * WIN + x1) * CCH + ck * 8]);
            short8 a10 = *reinterpret_cast<const short8*>(&sm[((size_t)y1 * WIN + x0) * CCH + ck * 8]);
            short8 a11 = *reinterpret_cast<const short8*>(&sm[((size_t)y1 * WIN + x1) * CCH + ck * 8]);
            float w00 = wy0 * wx0, w01 = wy0 * wx1, w10 = wy1 * wx0, w11 = wy1 * wx1;
#pragma unroll
            for (int j = 0; j < 8; ++j)
                v[j] = f2b(w00 * b2f(a00[j]) + w01 * b2f(a01[j])
                         + w10 * b2f(a10[j]) + w11 * b2f(a11[j]));
        }
        *reinterpret_cast<short8*>(&xs1[(((rr * SW + col) * CCH) + ck * 8) ^ swz(col)]) = v;
    }
    __syncthreads();

    int rL[2], cL[2];
#pragma unroll
    for (int pf = 0; pf < 2; ++pf) {
        int pl = (wpx * 2 + pf) * 16 + (lane & 15);
        cL[pf] = pl & (W - 1);
        rL[pf] = pl >> 3;
    }
    const int grpoff = (lane >> 4) * 8;

    // ===== phase A: conv layer 1 from xs1 -> xs2 =====
    {
        f32x4 acc[2][4] = {};
        const short* wl = g_wpack + ((size_t)1 * 9 * 4 * 8 * 64 + (size_t)(wco * 4) * 64 + lane) * 8;
        short8 wc0 = *reinterpret_cast<const short8*>(wl);
        short8 wc1 = *reinterpret_cast<const short8*>(wl + 512);
        short8 wc2 = *reinterpret_cast<const short8*>(wl + 1024);
        short8 wc3 = *reinterpret_cast<const short8*>(wl + 1536);
#pragma unroll
        for (int k = 0; k < 36; ++k) {
            short8 wn0 = wc0, wn1 = wc1, wn2 = wc2, wn3 = wc3;
            if (k + 1 < 36) {
                const short* wk = wl + (size_t)(k + 1) * 4096;
                wn0 = *reinterpret_cast<const short8*>(wk);
                wn1 = *reinterpret_cast<const short8*>(wk + 512);
                wn2 = *reinterpret_cast<const short8*>(wk + 1024);
                wn3 = *reinterpret_cast<const short8*>(wk + 1536);
            }
            const int tap = k >> 2, ch = k & 3;
            const int ky = tap / 3, kx = tap - ky * 3;
#pragma unroll
            for (int pf = 0; pf < 2; ++pf) {
                int col = cL[pf] + kx;
                int idx = (((rL[pf] + ky) * SW + col) * CCH + (ch << 5) + grpoff) ^ swz(col);
                short8 xf = *reinterpret_cast<const short8*>(&xs1[idx]);
                acc[pf][0] = __builtin_amdgcn_mfma_f32_16x16x32_bf16(wc0, xf, acc[pf][0], 0, 0, 0);
                acc[pf][1] = __builtin_amdgcn_mfma_f32_16x16x32_bf16(wc1, xf, acc[pf][1], 0, 0, 0);
                acc[pf][2] = __builtin_amdgcn_mfma_f32_16x16x32_bf16(wc2, xf, acc[pf][2], 0, 0, 0);
                acc[pf][3] = __builtin_amdgcn_mfma_f32_16x16x32_bf16(wc3, xf, acc[pf][3], 0, 0, 0);
            }
            wc0 = wn0; wc1 = wn1; wc2 = wn2; wc3 = wn3;
        }
        // epilogue layer 1 -> xs2 (fold style[2])
        float nz[2];
#pragma unroll
        for (int pf = 0; pf < 2; ++pf)
            nz[pf] = noise[(size_t)BS * 4096 + b * 4096 + (wpx * 2 + pf) * 16 + (lane & 15)];
#pragma unroll
        for (int cf = 0; cf < 4; ++cf) {
            const int coB = (wco * 4 + cf) * 16 + (lane >> 4) * 4;
            float rs[4], bw[4], bb[4], sn[4];
#pragma unroll
            for (int r = 0; r < 4; ++r) {
                rs[r] = g_rstd_all[((size_t)1 * BS + b) * CCH + coB + r];
                bw[r] = Bw[1 * CCH + coB + r];
                bb[r] = Bb[1 * CCH + coB + r];
                sn[r] = style2_s[coB + r];
            }
#pragma unroll
            for (int pf = 0; pf < 2; ++pf) {
                int px = (wpx * 2 + pf) * 16 + (lane & 15);
                int y = px >> 3, x = px & 7;
                short4v o;
#pragma unroll
                for (int r = 0; r < 4; ++r)
                    o[r] = f2b(leaky(acc[pf][cf][r] * rs[r] + nz[pf] * bw[r] + bb[r]) * sn[r]);
                int col = x + 1;
                *reinterpret_cast<short4v*>(&xs2[((((y + 1) * SW + col) * CCH) + coB) ^ swz(col)]) = o;
            }
        }
    }
    __syncthreads();

    // ===== phase B: conv layer 2 from xs2 -> global (fold style[3]) =====
    {
        f32x4 acc[2][4] = {};
        const short* wl = g_wpack + ((size_t)2 * 9 * 4 * 8 * 64 + (size_t)(wco * 4) * 64 + lane) * 8;
        short8 wc0 = *reinterpret_cast<const short8*>(wl);
        short8 wc1 = *reinterpret_cast<const short8*>(wl + 512);
        short8 wc2 = *reinterpret_cast<const short8*>(wl + 1024);
        short8 wc3 = *reinterpret_cast<const short8*>(wl + 1536);
#pragma unroll
        for (int k = 0; k < 36; ++k) {
            short8 wn0 = wc0, wn1 = wc1, wn2 = wc2, wn3 = wc3;
            if (k + 1 < 36) {
                const short* wk = wl + (size_t)(k + 1) * 4096;
                wn0 = *reinterpret_cast<const short8*>(wk);
                wn1 = *reinterpret_cast<const short8*>(wk + 512);
                wn2 = *reinterpret_cast<const short8*>(wk + 1024);
                wn3 = *reinterpret_cast<const short8*>(wk + 1536);
            }
            const int tap = k >> 2, ch = k & 3;
            const int ky = tap / 3, kx = tap - ky * 3;
#pragma unroll
            for (int pf = 0; pf < 2; ++pf) {
                int col = cL[pf] + kx;
                int idx = (((rL[pf] + ky) * SW + col) * CCH + (ch << 5) + grpoff) ^ swz(col);
                short8 xf = *reinterpret_cast<const short8*>(&xs2[idx]);
                acc[pf][0] = __builtin_amdgcn_mfma_f32_16x16x32_bf16(wc0, xf, acc[pf][0], 0, 0, 0);
                acc[pf][1] = __builtin_amdgcn_mfma_f32_16x16x32_bf16(wc1, xf, acc[pf][1], 0, 0, 0);
                acc[pf][2] = __builtin_amdgcn_mfma_f32_16x16x32_bf16(wc2, xf, acc[pf][2], 0, 0, 0);
                acc[pf][3] = __builtin_amdgcn_mfma_f32_16x16x32_bf16(wc3, xf, acc[pf][3], 0, 0, 0);
            }
            wc0 = wn0; wc1 = wn1; wc2 = wn2; wc3 = wn3;
        }
        float nz[2];
#pragma unroll
        for (int pf = 0; pf < 2; ++pf)
            nz[pf] = noise[(size_t)2 * BS * 4096 + b * 4096 + (wpx * 2 + pf) * 16 + (lane & 15)];
#pragma unroll
        for (int cf = 0; cf < 4; ++cf) {
            const int coB = (wco * 4 + cf) * 16 + (lane >> 4) * 4;
            float rs[4], bw[4], bb[4], sn[4];
#pragma unroll
            for (int r = 0; r < 4; ++r) {
                rs[r] = g_rstd_all[((size_t)2 * BS + b) * CCH + coB + r];
                bw[r] = Bw[2 * CCH + coB + r];
                bb[r] = Bb[2 * CCH + coB + r];
                sn[r] = style3_s[coB + r];
            }
#pragma unroll
            for (int pf = 0; pf < 2; ++pf) {
                int px = (wpx * 2 + pf) * 16 + (lane & 15);
                short4v o;
#pragma unroll
                for (int r = 0; r < 4; ++r)
                    o[r] = f2b(leaky(acc[pf][cf][r] * rs[r] + nz[pf] * bw[r] + bb[r]) * sn[r]);
                *reinterpret_cast<short4v*>(&g_bufA[((size_t)b * NS + px) * CCH + coB]) = o;
            }
        }
    }
}

// ---------------- MFMA modulated conv (NHWC bf16 in/out), layers 3..8 ----------------
// Block: 64 px x 128 co; 4 waves = 2 px-halves x 2 co-halves (2 pf x 4 cf each).
// UPM: 0 = plain staging; 1 = fused bilinear 2x upsample.
template<int LW, int UPM>
__global__ __launch_bounds__(256) void conv_mfma_kernel(
    int srcSel, int layer, int layerNext,
    const float* __restrict__ noise,
    const float* __restrict__ Bw, const float* __restrict__ Bb)
{
    constexpr int W = 1 << LW;
    constexpr int R = 64 >> LW;
    constexpr int SW = W + 2;
    constexpr int ROWS = R + 2;
    constexpr int NS = W * W;
    constexpr int WIN = W / 2;

    const short* xin = srcSel ? g_bufB : g_bufA;
    short* xout = srcSel ? g_bufA : g_bufB;

    const int b = blockIdx.y;
    const int pixBase = blockIdx.x * 64;
    const int rowBase = pixBase >> LW;
    const int tid = threadIdx.x;
    const int lane = tid & 63;
    const int wave = tid >> 6;
    const int wpx = wave & 1;
    const int wco = wave >> 1;

    __shared__ short xs[ROWS * SW * CCH];
    __shared__ float style_s[CCH];

    if (tid < CCH)
        style_s[tid] = layerNext ? g_style_all[((size_t)layerNext * BS + b) * CCH + tid] : 1.f;

    {
        const short* src = xin + (size_t)b * NS * CCH;
        const short* srcH = xin + (size_t)b * WIN * WIN * CCH;
        constexpr int UN = ROWS * SW * 16;
        for (int u = tid; u < UN; u += 256) {
            int ck = u & 15;
            int rem = u >> 4;
            int col = rem % SW;
            int rr = rem / SW;
            int gy = rowBase + rr - 1, gx = col - 1;
            short8 v = {0, 0, 0, 0, 0, 0, 0, 0};
            if (gy >= 0 && gy < W && gx >= 0 && gx < W) {
                if (UPM == 0) {
                    v = *reinterpret_cast<const short8*>(&src[((size_t)gy * W + gx) * CCH + ck * 8]);
                } else {
                    int y0, y1, x0, x1; float wy0, wy1, wx0, wx1;
                    uptaps(gy, WIN, y0, y1, wy0, wy1);
                    uptaps(gx, WIN, x0, x1, wx0, wx1);
                    short8 a00 = *reinterpret_cast<const short8*>(&srcH[((size_t)y0 * WIN + x0) * CCH + ck * 8]);
                    short8 a01 = *reinterpret_cast<const short8*>(&srcH[((size_t)y0 * WIN + x1) * CCH + ck * 8]);
                    short8 a10 = *reinterpret_cast<const short8*>(&srcH[((size_t)y1 * WIN + x0) * CCH + ck * 8]);
                    short8 a11 = *reinterpret_cast<const short8*>(&srcH[((size_t)y1 * WIN + x1) * CCH + ck * 8]);
                    float w00 = wy0 * wx0, w01 = wy0 * wx1, w10 = wy1 * wx0, w11 = wy1 * wx1;
#pragma unroll
                    for (int j = 0; j < 8; ++j)
                        v[j] = f2b(w00 * b2f(a00[j]) + w01 * b2f(a01[j])
                                 + w10 * b2f(a10[j]) + w11 * b2f(a11[j]));
                }
            }
            *reinterpret_cast<short8*>(&xs[(((rr * SW + col) * CCH) + ck * 8) ^ swz(col)]) = v;
        }
    }
    __syncthreads();

    int rL[2], cL[2];
#pragma unroll
    for (int pf = 0; pf < 2; ++pf) {
        int pl = (wpx * 2 + pf) * 16 + (lane & 15);
        cL[pf] = pl & (W - 1);
        rL[pf] = pl >> LW;
    }
    const int grpoff = (lane >> 4) * 8;

    f32x4 acc[2][4] = {};
    const short* wl = g_wpack + ((size_t)layer * 9 * 4 * 8 * 64
                                 + (size_t)(wco * 4) * 64 + lane) * 8;

    short8 wc0 = *reinterpret_cast<const short8*>(wl);
    short8 wc1 = *reinterpret_cast<const short8*>(wl + 512);
    short8 wc2 = *reinterpret_cast<const short8*>(wl + 1024);
    short8 wc3 = *reinterpret_cast<const short8*>(wl + 1536);
#pragma unroll
    for (int k = 0; k < 36; ++k) {
        short8 wn0 = wc0, wn1 = wc1, wn2 = wc2, wn3 = wc3;
        if (k + 1 < 36) {
            const short* wk = wl + (size_t)(k + 1) * 4096;
            wn0 = *reinterpret_cast<const short8*>(wk);
            wn1 = *reinterpret_cast<const short8*>(wk + 512);
            wn2 = *reinterpret_cast<const short8*>(wk + 1024);
            wn3 = *reinterpret_cast<const short8*>(wk + 1536);
        }
        const int tap = k >> 2, ch = k & 3;
        const int ky = tap / 3, kx = tap - ky * 3;
#pragma unroll
        for (int pf = 0; pf < 2; ++pf) {
            int col = cL[pf] + kx;
            int idx = (((rL[pf] + ky) * SW + col) * CCH + (ch << 5) + grpoff) ^ swz(col);
            short8 xf = *reinterpret_cast<const short8*>(&xs[idx]);
            acc[pf][0] = __builtin_amdgcn_mfma_f32_16x16x32_bf16(wc0, xf, acc[pf][0], 0, 0, 0);
            acc[pf][1] = __builtin_amdgcn_mfma_f32_16x16x32_bf16(wc1, xf, acc[pf][1], 0, 0, 0);
            acc[pf][2] = __builtin_amdgcn_mfma_f32_16x16x32_bf16(wc2, xf, acc[pf][2], 0, 0, 0);
            acc[pf][3] = __builtin_amdgcn_mfma_f32_16x16x32_bf16(wc3, xf, acc[pf][3], 0, 0, 0);
        }
        wc0 = wn0; wc1 = wn1; wc2 = wn2; wc3 = wn3;
    }

    float nz[2];
#pragma unroll
    for (int pf = 0; pf < 2; ++pf)
        nz[pf] = noise[b * 4096 + pixBase + (wpx * 2 + pf) * 16 + (lane & 15)];
#pragma unroll
    for (int cf = 0; cf < 4; ++cf) {
        const int coB = (wco * 4 + cf) * 16 + (lane >> 4) * 4;
        float rs[4], bw[4], bb[4], sn[4];
#pragma unroll
        for (int r = 0; r < 4; ++r) {
            rs[r] = g_rstd_all[((size_t)layer * BS + b) * CCH + coB + r];
            bw[r] = Bw[coB + r];
            bb[r] = Bb[coB + r];
            sn[r] = style_s[coB + r];
        }
#pragma unroll
        for (int pf = 0; pf < 2; ++pf) {
            int px = pixBase + (wpx * 2 + pf) * 16 + (lane & 15);
            short4v o;
#pragma unroll
            for (int r = 0; r < 4; ++r) {
                float v = leaky(acc[pf][cf][r] * rs[r] + nz[pf] * bw[r] + bb[r]) * sn[r];
                o[r] = f2b(v);
            }
            *reinterpret_cast<short4v*>(&xout[((size_t)b * NS + px) * CCH + coB]) = o;
        }
    }
}

// ---------------- MFMA toRGB (W=64; 3 real rows in 16-row M tile; waves split K) ----------------
__global__ __launch_bounds__(256) void rgb_mfma_kernel(
    int srcSel, const float* __restrict__ rgbb, float* __restrict__ out)
{
    constexpr int W = 64, SW = 66, ROWS = 3, NS = 4096;
    const short* xin = srcSel ? g_bufB : g_bufA;

    const int b = blockIdx.y;
    const int pixBase = blockIdx.x * 64;
    const int rowBase = pixBase >> 6;
    const int tid = threadIdx.x;
    const int lane = tid & 63;
    const int wave = tid >> 6;     // K-chunk

    __shared__ short xs[ROWS * SW * CCH];

    {
        const short* src = xin + (size_t)b * NS * CCH;
        constexpr int UN = ROWS * SW * 16;
        for (int u = tid; u < UN; u += 256) {
            int ck = u & 15;
            int rem = u >> 4;
            int col = rem % SW;
            int rr = rem / SW;
            int gy = rowBase + rr - 1, gx = col - 1;
            short8 v = {0, 0, 0, 0, 0, 0, 0, 0};
            if (gy >= 0 && gy < W && gx >= 0 && gx < W)
                v = *reinterpret_cast<const short8*>(&src[((size_t)gy * W + gx) * CCH + ck * 8]);
            *reinterpret_cast<short8*>(&xs[(((rr * SW + col) * CCH) + ck * 8) ^ swz(col)]) = v;
        }
    }
    __syncthreads();

    const int grpoff = (lane >> 4) * 8;
    const int cl = lane & 15;
    f32x4 acc[4] = {};
#pragma unroll
    for (int tap = 0; tap < 9; ++tap) {
        const int ky = tap / 3, kx = tap - ky * 3;
        short8 wf = *reinterpret_cast<const short8*>(
            &g_rgbpack[((size_t)(tap * 4 + wave) * 64 + lane) * 8]);
#pragma unroll
        for (int pf = 0; pf < 4; ++pf) {
            int col = cl + pf * 16 + kx;
            int idx = ((ky * SW + col) * CCH + (wave << 5) + grpoff) ^ swz(col);
            short8 xf = *reinterpret_cast<const short8*>(&xs[idx]);
            acc[pf] = __builtin_amdgcn_mfma_f32_16x16x32_bf16(wf, xf, acc[pf], 0, 0, 0);
        }
    }
    __syncthreads();
    float* red = reinterpret_cast<float*>(xs);
    if (wave > 0) {
#pragma unroll
        for (int pf = 0; pf < 4; ++pf)
#pragma unroll
            for (int r = 0; r < 4; ++r)
                red[(((wave - 1) * 4 + pf) * 64 + lane) * 4 + r] = acc[pf][r];
    }
    __syncthreads();
    if (wave == 0 && (lane >> 4) == 0) {
#pragma unroll
        for (int pf = 0; pf < 4; ++pf) {
            int px = pixBase + pf * 16 + cl;
#pragma unroll
            for (int r = 0; r < 3; ++r) {
                float s = acc[pf][r];
#pragma unroll
                for (int wv = 0; wv < 3; ++wv)
                    s += red[((wv * 4 + pf) * 64 + lane) * 4 + r];
                out[(size_t)(b * 3 + r) * NS + px] = s + rgbb[r];
            }
        }
    }
}

// ---------------- launch ----------------
extern "C" void kernel_launch(void* const* d_in, const int* in_sizes, int n_in,
                              void* d_out, int out_size, void* d_ws, size_t ws_size,
                              hipStream_t stream)
{
    const float* latent = (const float*)d_in[0];
    const float* noise  = (const float*)d_in[1];
    const float* map_w  = (const float*)d_in[2];
    const float* map_b  = (const float*)d_in[3];
    const float* A_w    = (const float*)d_in[4];
    const float* A_b    = (const float*)d_in[5];
    const float* B_w    = (const float*)d_in[6];
    const float* B_b    = (const float*)d_in[7];
    const float* conv_w = (const float*)d_in[8];
    const float* rgb_w  = (const float*)d_in[9];
    const float* rgb_b  = (const float*)d_in[10];
    float* out = (float*)d_out;
    (void)d_ws; (void)ws_size;

    prep_kernel<<<(WPN + RGBN + S2N + 255) / 256, 256, 0, stream>>>(conv_w, rgb_w);

    int wsel = 0;
    for (int i = 0; i < LMAP; ++i) {
        map_fc_kernel<<<dim3(8, BS), 256, 0, stream>>>(
            wsel, i == 0 ? 1 : 0, latent, map_w + (size_t)i * D * D, map_b + i * D);
        wsel ^= 1;
    }

    style_rstd_kernel<<<dim3(8, BS), 256, 0, stream>>>(A_w, A_b);

    // layers 1+2 fused (8x8) -> g_bufA
    conv8_pair_kernel<<<BS, 256, 0, stream>>>(noise, B_w, B_b);

    int cur = 0;   // data in g_bufA
    int Hc = 8;
    for (int i = 3; i < NLAYERS; ++i) {
        if (i & 1) Hc *= 2;
        int ns = Hc * Hc;
        int lnext = (i < 8) ? (i + 1) : 0;
        dim3 grid(ns / 64, BS);
        const float* nz = noise + (size_t)i * BS * 4096;
        switch (i) {
            case 3: conv_mfma_kernel<4, 1><<<grid, 256, 0, stream>>>(cur, i, lnext, nz, B_w + i * CCH, B_b + i * CCH); break;
            case 4: conv_mfma_kernel<4, 0><<<grid, 256, 0, stream>>>(cur, i, lnext, nz, B_w + i * CCH, B_b + i * CCH); break;
            case 5: conv_mfma_kernel<5, 1><<<grid, 256, 0, stream>>>(cur, i, lnext, nz, B_w + i * CCH, B_b + i * CCH); break;
            case 6: conv_mfma_kernel<5, 0><<<grid, 256, 0, stream>>>(cur, i, lnext, nz, B_w + i * CCH, B_b + i * CCH); break;
            case 7: conv_mfma_kernel<6, 1><<<grid, 256, 0, stream>>>(cur, i, lnext, nz, B_w + i * CCH, B_b + i * CCH); break;
            case 8: conv_mfma_kernel<6, 0><<<grid, 256, 0, stream>>>(cur, i, lnext, nz, B_w + i * CCH, B_b + i * CCH); break;
        }
        cur ^= 1;
    }

    rgb_mfma_kernel<<<dim3(64, BS), 256, 0, stream>>>(cur, rgb_b, out);
}

// Round 13
// 207.457 us; speedup vs baseline: 1.5226x; 1.0182x over previous
//
#include <hip/hip_runtime.h>
#include <hip/hip_bf16.h>

#define BS 8
#define D 512
#define CCH 128
#define LMAP 8
#define NLAYERS 9

typedef short short8 __attribute__((ext_vector_type(8)));
typedef short short4v __attribute__((ext_vector_type(4)));
typedef float f32x4 __attribute__((ext_vector_type(4)));

// ---- module-global scratch ----
__device__ short g_bufA[(size_t)BS * 4096 * CCH];   // bf16 NHWC [b][px][ci]
__device__ short g_bufB[(size_t)BS * 4096 * CCH];
__device__ float g_w[2][BS * D];
__device__ float g_style_all[NLAYERS * BS * CCH];
__device__ float g_rstd_all[NLAYERS * BS * CCH];
__device__ float g_s2[(size_t)NLAYERS * CCH * CCH];              // S2[l][co][ci] = sum_tap w^2
__device__ short g_wpack[(size_t)NLAYERS * 9 * 4 * 8 * 64 * 8];  // packed bf16 W-frags
__device__ short g_rgbpack[9 * 4 * 64 * 8];

__device__ __forceinline__ float leaky(float v) { return v >= 0.f ? v : 0.2f * v; }
__device__ __forceinline__ short f2b(float f) {
    __hip_bfloat16 h = __float2bfloat16(f);
    return *reinterpret_cast<short*>(&h);
}
__device__ __forceinline__ float b2f(short s) {
    return __uint_as_float(((unsigned int)(unsigned short)s) << 16);
}
__device__ __forceinline__ int swz(int col) { return ((col ^ (col >> 3)) & 7) << 3; }

__device__ __forceinline__ void uptaps(int o, int Win, int& i0, int& i1, float& w0, float& w1)
{
    int m = o >> 1;
    if ((o & 1) == 0) { i0 = m - 1; i1 = m; w0 = 0.25f; w1 = 0.75f; if (i0 < 0) { i0 = 0; w0 = 0.f; w1 = 1.f; } }
    else              { i0 = m; i1 = m + 1; w0 = 0.75f; w1 = 0.25f; if (i1 >= Win) { i1 = Win - 1; w0 = 1.f; w1 = 0.f; } }
}

// ---------------- fused prep: wpack + rgbpack + S2 ----------------
#define WPN (NLAYERS * 9 * 4 * 8 * 64)
#define RGBN (9 * 4 * 64)
#define S2N (NLAYERS * CCH * CCH)
__global__ __launch_bounds__(256) void prep_kernel(
    const float* __restrict__ convw, const float* __restrict__ rgbw)
{
    int idx = blockIdx.x * 256 + threadIdx.x;
    if (idx < WPN) {
        int lane = idx & 63;
        int cogrp = (idx >> 6) & 7;
        int chunk = (idx >> 9) & 3;
        int t = idx >> 11;
        int layer = t / 9, tap = t - layer * 9;
        int co = cogrp * 16 + (lane & 15);
        int ci0 = chunk * 32 + (lane >> 4) * 8;
        short8 v;
#pragma unroll
        for (int j = 0; j < 8; ++j)
            v[j] = f2b(convw[(((size_t)layer * CCH + co) * CCH + ci0 + j) * 9 + tap]);
        *reinterpret_cast<short8*>(&g_wpack[(size_t)idx * 8]) = v;
    } else if (idx < WPN + RGBN) {
        int u = idx - WPN;
        int lane = u & 63;
        int chunk = (u >> 6) & 3;
        int tap = u >> 8;
        int co = lane & 15;
        int ci0 = chunk * 32 + (lane >> 4) * 8;
        short8 v;
#pragma unroll
        for (int j = 0; j < 8; ++j)
            v[j] = (co < 3) ? f2b(rgbw[((size_t)(co * CCH) + ci0 + j) * 9 + tap]) : (short)0;
        *reinterpret_cast<short8*>(&g_rgbpack[(size_t)u * 8]) = v;
    } else if (idx < WPN + RGBN + S2N) {
        int u = idx - WPN - RGBN;         // [l][co][ci]
        const float* wp = convw + (size_t)u * 9;
        float s = 0.f;
#pragma unroll
        for (int t = 0; t < 9; ++t) { float m = wp[t]; s += m * m; }
        g_s2[u] = s;
    }
}

// ---------------- Mapping FC (64 blocks/layer, pixelnorm in layer 0, 16-deep ILP) ----------------
__global__ __launch_bounds__(256) void map_fc_kernel(
    int srcSel, int useZ, const float* __restrict__ z,
    const float* __restrict__ W, const float* __restrict__ bias)
{
    float* wout = g_w[srcSel ^ 1];
    int b = blockIdx.y;
    int jb = blockIdx.x * 64;
    int tid = threadIdx.x;
    int jl = tid & 63, kp = tid >> 6;
    __shared__ float xin[D];
    __shared__ float part[4][64];
    __shared__ float wred[4];
    if (useZ) {
        xin[tid] = z[b * D + tid];
        xin[tid + 256] = z[b * D + tid + 256];
    } else {
        const float* win = g_w[srcSel];
        xin[tid] = win[b * D + tid];
        xin[tid + 256] = win[b * D + tid + 256];
    }
    __syncthreads();
    if (useZ) {
        float p = xin[tid] * xin[tid] + xin[tid + 256] * xin[tid + 256];
#pragma unroll
        for (int off = 32; off > 0; off >>= 1) p += __shfl_down(p, off, 64);
        if ((tid & 63) == 0) wred[tid >> 6] = p;
        __syncthreads();
        float ss = wred[0] + wred[1] + wred[2] + wred[3];
        float r = rsqrtf(ss * (1.f / 512.f) + 1e-8f);
        xin[tid] *= r; xin[tid + 256] *= r;
        __syncthreads();
    }
    const float* Wp = W + jb + jl;
    const int k0 = kp * 128;
    float a[16];
#pragma unroll
    for (int j = 0; j < 16; ++j) a[j] = 0.f;
    for (int k = k0; k < k0 + 128; k += 16) {
#pragma unroll
        for (int j = 0; j < 16; ++j)
            a[j] += xin[k + j] * Wp[(size_t)(k + j) * D];
    }
    float s8 = 0.f;
#pragma unroll
    for (int j = 0; j < 16; ++j) s8 += a[j];
    part[kp][jl] = s8;
    __syncthreads();
    if (tid < 64) {
        float s = part[0][tid] + part[1][tid] + part[2][tid] + part[3][tid] + bias[jb + tid];
        wout[b * D + jb + tid] = leaky(s);
    }
}

// ---------------- style + rstd for ALL layers (rstd via S2), one dispatch ----------------
__global__ __launch_bounds__(256) void style_rstd_kernel(
    const float* __restrict__ Aw, const float* __restrict__ Ab)
{
    int l = blockIdx.x + 1;        // layers 1..8
    int b = blockIdx.y;
    int tid = threadIdx.x;
    __shared__ float ws_[D];
    __shared__ float part[2][CCH];
    __shared__ float st[CCH];
    ws_[tid] = g_w[0][b * D + tid];
    ws_[tid + 256] = g_w[0][b * D + tid + 256];
    __syncthreads();
    {
        int c = tid & 127, kh = tid >> 7;
        const float* Ap = Aw + (size_t)l * D * CCH + c;
        const int k0 = kh * 256;
        float a0 = 0.f, a1 = 0.f, a2 = 0.f, a3 = 0.f, a4 = 0.f, a5 = 0.f, a6 = 0.f, a7 = 0.f;
        for (int k = k0; k < k0 + 256; k += 8) {
            a0 += ws_[k + 0] * Ap[(size_t)(k + 0) * CCH];
            a1 += ws_[k + 1] * Ap[(size_t)(k + 1) * CCH];
            a2 += ws_[k + 2] * Ap[(size_t)(k + 2) * CCH];
            a3 += ws_[k + 3] * Ap[(size_t)(k + 3) * CCH];
            a4 += ws_[k + 4] * Ap[(size_t)(k + 4) * CCH];
            a5 += ws_[k + 5] * Ap[(size_t)(k + 5) * CCH];
            a6 += ws_[k + 6] * Ap[(size_t)(k + 6) * CCH];
            a7 += ws_[k + 7] * Ap[(size_t)(k + 7) * CCH];
        }
        part[kh][c] = ((a0 + a1) + (a2 + a3)) + ((a4 + a5) + (a6 + a7));
    }
    __syncthreads();
    if (tid < CCH) {
        float s = part[0][tid] + part[1][tid] + Ab[l * CCH + tid];
        st[tid] = s;
        g_style_all[((size_t)l * BS + b) * CCH + tid] = s;
    }
    __syncthreads();
    int colid = tid >> 4, kpart = tid & 15;
#pragma unroll
    for (int co8 = 0; co8 < 8; ++co8) {
        int cout = co8 * 16 + colid;
        const float* sp = g_s2 + ((size_t)l * CCH + cout) * CCH + kpart * 8;
        float s = 0.f;
#pragma unroll
        for (int j = 0; j < 8; ++j) { float sv = st[kpart * 8 + j]; s += sv * sv * sp[j]; }
#pragma unroll
        for (int off = 8; off > 0; off >>= 1) s += __shfl_down(s, off, 16);
        if (kpart == 0) g_rstd_all[((size_t)l * BS + b) * CCH + cout] = rsqrtf(s + 1e-8f);
    }
}

// ---------------- fused conv layers 1+2 (both 8x8), one block per batch ----------------
__global__ __launch_bounds__(256) void conv8_pair_kernel(
    const float* __restrict__ noise,
    const float* __restrict__ Bw, const float* __restrict__ Bb)
{
    constexpr int W = 8, SW = 10, ROWS = 10, NS = 64, WIN = 4;
    const int b = blockIdx.x;
    const int tid = threadIdx.x;
    const int lane = tid & 63;
    const int wave = tid >> 6;
    const int wpx = wave & 1;
    const int wco = wave >> 1;

    __shared__ short xs1[ROWS * SW * CCH];
    __shared__ short xs2[ROWS * SW * CCH];
    __shared__ short sm[16 * CCH];
    __shared__ float style2_s[CCH], style3_s[CCH];

    if (tid < CCH) {
        style2_s[tid] = g_style_all[((size_t)2 * BS + b) * CCH + tid];
        style3_s[tid] = g_style_all[((size_t)3 * BS + b) * CCH + tid];
    }
    for (int u = tid; u < 16 * CCH; u += 256) {
        int c = u & 127;
        int pp = u >> 7;
        float v = leaky(noise[b * 4096 + pp] * Bw[c] + Bb[c])
                  * g_style_all[((size_t)1 * BS + b) * CCH + c];
        sm[u] = f2b(v);
    }
    for (int u = tid; u < ROWS * SW * 16; u += 256) {
        int ck = u & 15;
        int cell = u >> 4;
        int col = cell % SW;
        int rr = cell / SW;
        if (rr >= 1 && rr <= 8 && col >= 1 && col <= 8) continue;
        short8 zz = {0, 0, 0, 0, 0, 0, 0, 0};
        *reinterpret_cast<short8*>(&xs2[(((rr * SW + col) * CCH) + ck * 8) ^ swz(col)]) = zz;
    }
    __syncthreads();

    for (int u = tid; u < ROWS * SW * 16; u += 256) {
        int ck = u & 15;
        int rem = u >> 4;
        int col = rem % SW;
        int rr = rem / SW;
        int gy = rr - 1, gx = col - 1;
        short8 v = {0, 0, 0, 0, 0, 0, 0, 0};
        if (gy >= 0 && gy < W && gx >= 0 && gx < W) {
            int y0, y1, x0, x1; float wy0, wy1, wx0, wx1;
            uptaps(gy, WIN, y0, y1, wy0, wy1);
            uptaps(gx, WIN, x0, x1, wx0, wx1);
            short8 a00 = *reinterpret_cast<const short8*>(&sm[((size_t)y0 * WIN + x0) * CCH + ck * 8]);
            short8 a01 = *reinterpret_cast<const short8*>(&sm[((size_t)y0 * WIN + x1) * CCH + ck * 8]);
            short8 a10 = *reinterpret_cast<const short8*>(&sm[((size_t)y1 * WIN + x0) * CCH + ck * 8]);
            short8 a11 = *reinterpret_cast<const short8*>(&sm[((size_t)y1 * WIN + x1) * CCH + ck * 8]);
            float w00 = wy0 * wx0, w01 = wy0 * wx1, w10 = wy1 * wx0, w11 = wy1 * wx1;
#pragma unroll
            for (int j = 0; j < 8; ++j)
                v[j] = f2b(w00 * b2f(a00[j]) + w01 * b2f(a01[j])
                         + w10 * b2f(a10[j]) + w11 * b2f(a11[j]));
        }
        *reinterpret_cast<short8*>(&xs1[(((rr * SW + col) * CCH) + ck * 8) ^ swz(col)]) = v;
    }
    __syncthreads();

    int rL[2], cL[2];
#pragma unroll
    for (int pf = 0; pf < 2; ++pf) {
        int pl = (wpx * 2 + pf) * 16 + (lane & 15);
        cL[pf] = pl & (W - 1);
        rL[pf] = pl >> 3;
    }
    const int grpoff = (lane >> 4) * 8;

    // phase A: conv layer 1 -> xs2
    {
        f32x4 acc[2][4] = {};
        const short* wl = g_wpack + ((size_t)1 * 9 * 4 * 8 * 64 + (size_t)(wco * 4) * 64 + lane) * 8;
        short8 wc0 = *reinterpret_cast<const short8*>(wl);
        short8 wc1 = *reinterpret_cast<const short8*>(wl + 512);
        short8 wc2 = *reinterpret_cast<const short8*>(wl + 1024);
        short8 wc3 = *reinterpret_cast<const short8*>(wl + 1536);
#pragma unroll
        for (int k = 0; k < 36; ++k) {
            short8 wn0 = wc0, wn1 = wc1, wn2 = wc2, wn3 = wc3;
            if (k + 1 < 36) {
                const short* wk = wl + (size_t)(k + 1) * 4096;
                wn0 = *reinterpret_cast<const short8*>(wk);
                wn1 = *reinterpret_cast<const short8*>(wk + 512);
                wn2 = *reinterpret_cast<const short8*>(wk + 1024);
                wn3 = *reinterpret_cast<const short8*>(wk + 1536);
            }
            const int tap = k >> 2, ch = k & 3;
            const int ky = tap / 3, kx = tap - ky * 3;
#pragma unroll
            for (int pf = 0; pf < 2; ++pf) {
                int col = cL[pf] + kx;
                int idx = (((rL[pf] + ky) * SW + col) * CCH + (ch << 5) + grpoff) ^ swz(col);
                short8 xf = *reinterpret_cast<const short8*>(&xs1[idx]);
                acc[pf][0] = __builtin_amdgcn_mfma_f32_16x16x32_bf16(wc0, xf, acc[pf][0], 0, 0, 0);
                acc[pf][1] = __builtin_amdgcn_mfma_f32_16x16x32_bf16(wc1, xf, acc[pf][1], 0, 0, 0);
                acc[pf][2] = __builtin_amdgcn_mfma_f32_16x16x32_bf16(wc2, xf, acc[pf][2], 0, 0, 0);
                acc[pf][3] = __builtin_amdgcn_mfma_f32_16x16x32_bf16(wc3, xf, acc[pf][3], 0, 0, 0);
            }
            wc0 = wn0; wc1 = wn1; wc2 = wn2; wc3 = wn3;
        }
        float nz[2];
#pragma unroll
        for (int pf = 0; pf < 2; ++pf)
            nz[pf] = noise[(size_t)BS * 4096 + b * 4096 + (wpx * 2 + pf) * 16 + (lane & 15)];
#pragma unroll
        for (int cf = 0; cf < 4; ++cf) {
            const int coB = (wco * 4 + cf) * 16 + (lane >> 4) * 4;
            float rs[4], bw[4], bb[4], sn[4];
#pragma unroll
            for (int r = 0; r < 4; ++r) {
                rs[r] = g_rstd_all[((size_t)1 * BS + b) * CCH + coB + r];
                bw[r] = Bw[1 * CCH + coB + r];
                bb[r] = Bb[1 * CCH + coB + r];
                sn[r] = style2_s[coB + r];
            }
#pragma unroll
            for (int pf = 0; pf < 2; ++pf) {
                int px = (wpx * 2 + pf) * 16 + (lane & 15);
                int y = px >> 3, x = px & 7;
                short4v o;
#pragma unroll
                for (int r = 0; r < 4; ++r)
                    o[r] = f2b(leaky(acc[pf][cf][r] * rs[r] + nz[pf] * bw[r] + bb[r]) * sn[r]);
                int col = x + 1;
                *reinterpret_cast<short4v*>(&xs2[((((y + 1) * SW + col) * CCH) + coB) ^ swz(col)]) = o;
            }
        }
    }
    __syncthreads();

    // phase B: conv layer 2 -> global
    {
        f32x4 acc[2][4] = {};
        const short* wl = g_wpack + ((size_t)2 * 9 * 4 * 8 * 64 + (size_t)(wco * 4) * 64 + lane) * 8;
        short8 wc0 = *reinterpret_cast<const short8*>(wl);
        short8 wc1 = *reinterpret_cast<const short8*>(wl + 512);
        short8 wc2 = *reinterpret_cast<const short8*>(wl + 1024);
        short8 wc3 = *reinterpret_cast<const short8*>(wl + 1536);
#pragma unroll
        for (int k = 0; k < 36; ++k) {
            short8 wn0 = wc0, wn1 = wc1, wn2 = wc2, wn3 = wc3;
            if (k + 1 < 36) {
                const short* wk = wl + (size_t)(k + 1) * 4096;
                wn0 = *reinterpret_cast<const short8*>(wk);
                wn1 = *reinterpret_cast<const short8*>(wk + 512);
                wn2 = *reinterpret_cast<const short8*>(wk + 1024);
                wn3 = *reinterpret_cast<const short8*>(wk + 1536);
            }
            const int tap = k >> 2, ch = k & 3;
            const int ky = tap / 3, kx = tap - ky * 3;
#pragma unroll
            for (int pf = 0; pf < 2; ++pf) {
                int col = cL[pf] + kx;
                int idx = (((rL[pf] + ky) * SW + col) * CCH + (ch << 5) + grpoff) ^ swz(col);
                short8 xf = *reinterpret_cast<const short8*>(&xs2[idx]);
                acc[pf][0] = __builtin_amdgcn_mfma_f32_16x16x32_bf16(wc0, xf, acc[pf][0], 0, 0, 0);
                acc[pf][1] = __builtin_amdgcn_mfma_f32_16x16x32_bf16(wc1, xf, acc[pf][1], 0, 0, 0);
                acc[pf][2] = __builtin_amdgcn_mfma_f32_16x16x32_bf16(wc2, xf, acc[pf][2], 0, 0, 0);
                acc[pf][3] = __builtin_amdgcn_mfma_f32_16x16x32_bf16(wc3, xf, acc[pf][3], 0, 0, 0);
            }
            wc0 = wn0; wc1 = wn1; wc2 = wn2; wc3 = wn3;
        }
        float nz[2];
#pragma unroll
        for (int pf = 0; pf < 2; ++pf)
            nz[pf] = noise[(size_t)2 * BS * 4096 + b * 4096 + (wpx * 2 + pf) * 16 + (lane & 15)];
#pragma unroll
        for (int cf = 0; cf < 4; ++cf) {
            const int coB = (wco * 4 + cf) * 16 + (lane >> 4) * 4;
            float rs[4], bw[4], bb[4], sn[4];
#pragma unroll
            for (int r = 0; r < 4; ++r) {
                rs[r] = g_rstd_all[((size_t)2 * BS + b) * CCH + coB + r];
                bw[r] = Bw[2 * CCH + coB + r];
                bb[r] = Bb[2 * CCH + coB + r];
                sn[r] = style3_s[coB + r];
            }
#pragma unroll
            for (int pf = 0; pf < 2; ++pf) {
                int px = (wpx * 2 + pf) * 16 + (lane & 15);
                short4v o;
#pragma unroll
                for (int r = 0; r < 4; ++r)
                    o[r] = f2b(leaky(acc[pf][cf][r] * rs[r] + nz[pf] * bw[r] + bb[r]) * sn[r]);
                *reinterpret_cast<short4v*>(&g_bufA[((size_t)b * NS + px) * CCH + coB]) = o;
            }
        }
    }
}

// ---------------- MFMA modulated conv (NHWC bf16), layers 3..8 ----------------
// Tile = TW x TH px (TW*TH = 64), TLW = log2(TW). Block covers 128 co; 4 waves
// = 2 px-halves x 2 co-halves (2 pf x 4 cf each). UPM: 0 plain, 1 fused upsample.
template<int LW, int UPM, int TLW>
__global__ __launch_bounds__(256) void conv_mfma_kernel(
    int srcSel, int layer, int layerNext,
    const float* __restrict__ noise,
    const float* __restrict__ Bw, const float* __restrict__ Bb)
{
    constexpr int W = 1 << LW;
    constexpr int TW = 1 << TLW;
    constexpr int TH = 64 >> TLW;
    constexpr int SW = TW + 2;
    constexpr int ROWS = TH + 2;
    constexpr int NS = W * W;
    constexpr int WIN = W / 2;
    constexpr int TILES_X = W / TW;

    const short* xin = srcSel ? g_bufB : g_bufA;
    short* xout = srcSel ? g_bufA : g_bufB;

    const int b = blockIdx.y;
    const int tx = blockIdx.x & (TILES_X - 1);
    const int ty = blockIdx.x >> (LW - TLW);
    const int rowBase = ty * TH;
    const int colBase = tx * TW;
    const int tid = threadIdx.x;
    const int lane = tid & 63;
    const int wave = tid >> 6;
    const int wpx = wave & 1;
    const int wco = wave >> 1;

    __shared__ short xs[ROWS * SW * CCH];
    __shared__ float style_s[CCH];

    if (tid < CCH)
        style_s[tid] = layerNext ? g_style_all[((size_t)layerNext * BS + b) * CCH + tid] : 1.f;

    {
        const short* src = xin + (size_t)b * NS * CCH;
        const short* srcH = xin + (size_t)b * WIN * WIN * CCH;
        constexpr int UN = ROWS * SW * 16;
        for (int u = tid; u < UN; u += 256) {
            int ck = u & 15;
            int rem = u >> 4;
            int col = rem % SW;
            int rr = rem / SW;
            int gy = rowBase + rr - 1, gx = colBase + col - 1;
            short8 v = {0, 0, 0, 0, 0, 0, 0, 0};
            if (gy >= 0 && gy < W && gx >= 0 && gx < W) {
                if (UPM == 0) {
                    v = *reinterpret_cast<const short8*>(&src[((size_t)gy * W + gx) * CCH + ck * 8]);
                } else {
                    int y0, y1, x0, x1; float wy0, wy1, wx0, wx1;
                    uptaps(gy, WIN, y0, y1, wy0, wy1);
                    uptaps(gx, WIN, x0, x1, wx0, wx1);
                    short8 a00 = *reinterpret_cast<const short8*>(&srcH[((size_t)y0 * WIN + x0) * CCH + ck * 8]);
                    short8 a01 = *reinterpret_cast<const short8*>(&srcH[((size_t)y0 * WIN + x1) * CCH + ck * 8]);
                    short8 a10 = *reinterpret_cast<const short8*>(&srcH[((size_t)y1 * WIN + x0) * CCH + ck * 8]);
                    short8 a11 = *reinterpret_cast<const short8*>(&srcH[((size_t)y1 * WIN + x1) * CCH + ck * 8]);
                    float w00 = wy0 * wx0, w01 = wy0 * wx1, w10 = wy1 * wx0, w11 = wy1 * wx1;
#pragma unroll
                    for (int j = 0; j < 8; ++j)
                        v[j] = f2b(w00 * b2f(a00[j]) + w01 * b2f(a01[j])
                                 + w10 * b2f(a10[j]) + w11 * b2f(a11[j]));
                }
            }
            *reinterpret_cast<short8*>(&xs[(((rr * SW + col) * CCH) + ck * 8) ^ swz(col)]) = v;
        }
    }
    __syncthreads();

    int rL[2], cL[2];
#pragma unroll
    for (int pf = 0; pf < 2; ++pf) {
        int pl = (wpx * 2 + pf) * 16 + (lane & 15);
        cL[pf] = pl & (TW - 1);
        rL[pf] = pl >> TLW;
    }
    const int grpoff = (lane >> 4) * 8;

    f32x4 acc[2][4] = {};
    const short* wl = g_wpack + ((size_t)layer * 9 * 4 * 8 * 64
                                 + (size_t)(wco * 4) * 64 + lane) * 8;

    short8 wc0 = *reinterpret_cast<const short8*>(wl);
    short8 wc1 = *reinterpret_cast<const short8*>(wl + 512);
    short8 wc2 = *reinterpret_cast<const short8*>(wl + 1024);
    short8 wc3 = *reinterpret_cast<const short8*>(wl + 1536);
#pragma unroll
    for (int k = 0; k < 36; ++k) {
        short8 wn0 = wc0, wn1 = wc1, wn2 = wc2, wn3 = wc3;
        if (k + 1 < 36) {
            const short* wk = wl + (size_t)(k + 1) * 4096;
            wn0 = *reinterpret_cast<const short8*>(wk);
            wn1 = *reinterpret_cast<const short8*>(wk + 512);
            wn2 = *reinterpret_cast<const short8*>(wk + 1024);
            wn3 = *reinterpret_cast<const short8*>(wk + 1536);
        }
        const int tap = k >> 2, ch = k & 3;
        const int ky = tap / 3, kx = tap - ky * 3;
#pragma unroll
        for (int pf = 0; pf < 2; ++pf) {
            int col = cL[pf] + kx;
            int idx = (((rL[pf] + ky) * SW + col) * CCH + (ch << 5) + grpoff) ^ swz(col);
            short8 xf = *reinterpret_cast<const short8*>(&xs[idx]);
            acc[pf][0] = __builtin_amdgcn_mfma_f32_16x16x32_bf16(wc0, xf, acc[pf][0], 0, 0, 0);
            acc[pf][1] = __builtin_amdgcn_mfma_f32_16x16x32_bf16(wc1, xf, acc[pf][1], 0, 0, 0);
            acc[pf][2] = __builtin_amdgcn_mfma_f32_16x16x32_bf16(wc2, xf, acc[pf][2], 0, 0, 0);
            acc[pf][3] = __builtin_amdgcn_mfma_f32_16x16x32_bf16(wc3, xf, acc[pf][3], 0, 0, 0);
        }
        wc0 = wn0; wc1 = wn1; wc2 = wn2; wc3 = wn3;
    }

    float nz[2];
    int pxg[2];
#pragma unroll
    for (int pf = 0; pf < 2; ++pf) {
        int pl = (wpx * 2 + pf) * 16 + (lane & 15);
        int x = pl & (TW - 1), y = pl >> TLW;
        pxg[pf] = (rowBase + y) * W + colBase + x;
        nz[pf] = noise[b * 4096 + pxg[pf]];
    }
#pragma unroll
    for (int cf = 0; cf < 4; ++cf) {
        const int coB = (wco * 4 + cf) * 16 + (lane >> 4) * 4;
        float rs[4], bw[4], bb[4], sn[4];
#pragma unroll
        for (int r = 0; r < 4; ++r) {
            rs[r] = g_rstd_all[((size_t)layer * BS + b) * CCH + coB + r];
            bw[r] = Bw[coB + r];
            bb[r] = Bb[coB + r];
            sn[r] = style_s[coB + r];
        }
#pragma unroll
        for (int pf = 0; pf < 2; ++pf) {
            short4v o;
#pragma unroll
            for (int r = 0; r < 4; ++r) {
                float v = leaky(acc[pf][cf][r] * rs[r] + nz[pf] * bw[r] + bb[r]) * sn[r];
                o[r] = f2b(v);
            }
            *reinterpret_cast<short4v*>(&xout[((size_t)b * NS + pxg[pf]) * CCH + coB]) = o;
        }
    }
}

// ---------------- MFMA toRGB (W=64; 32x2 tiles; 3 real rows in 16-row M; waves split K) ----------------
__global__ __launch_bounds__(256) void rgb_mfma_kernel(
    int srcSel, const float* __restrict__ rgbb, float* __restrict__ out)
{
    constexpr int W = 64, TW = 32, TH = 2, SW = 34, ROWS = 4, NS = 4096;
    const short* xin = srcSel ? g_bufB : g_bufA;

    const int b = blockIdx.y;
    const int tx = blockIdx.x & 1;
    const int ty = blockIdx.x >> 1;
    const int rowBase = ty * TH;
    const int colBase = tx * TW;
    const int tid = threadIdx.x;
    const int lane = tid & 63;
    const int wave = tid >> 6;     // K-chunk

    __shared__ short xs[ROWS * SW * CCH];

    {
        const short* src = xin + (size_t)b * NS * CCH;
        constexpr int UN = ROWS * SW * 16;
        for (int u = tid; u < UN; u += 256) {
            int ck = u & 15;
            int rem = u >> 4;
            int col = rem % SW;
            int rr = rem / SW;
            int gy = rowBase + rr - 1, gx = colBase + col - 1;
            short8 v = {0, 0, 0, 0, 0, 0, 0, 0};
            if (gy >= 0 && gy < W && gx >= 0 && gx < W)
                v = *reinterpret_cast<const short8*>(&src[((size_t)gy * W + gx) * CCH + ck * 8]);
            *reinterpret_cast<short8*>(&xs[(((rr * SW + col) * CCH) + ck * 8) ^ swz(col)]) = v;
        }
    }
    __syncthreads();

    const int grpoff = (lane >> 4) * 8;
    const int cl = lane & 15;
    f32x4 acc[4] = {};
#pragma unroll
    for (int tap = 0; tap < 9; ++tap) {
        const int ky = tap / 3, kx = tap - ky * 3;
        short8 wf = *reinterpret_cast<const short8*>(
            &g_rgbpack[((size_t)(tap * 4 + wave) * 64 + lane) * 8]);
#pragma unroll
        for (int pf = 0; pf < 4; ++pf) {
            int pl = pf * 16 + cl;
            int x = pl & (TW - 1), y = pl >> 5;
            int col = x + kx;
            int idx = (((y + ky) * SW + col) * CCH + (wave << 5) + grpoff) ^ swz(col);
            short8 xf = *reinterpret_cast<const short8*>(&xs[idx]);
            acc[pf] = __builtin_amdgcn_mfma_f32_16x16x32_bf16(wf, xf, acc[pf], 0, 0, 0);
        }
    }
    __syncthreads();
    float* red = reinterpret_cast<float*>(xs);
    if (wave > 0) {
#pragma unroll
        for (int pf = 0; pf < 4; ++pf)
#pragma unroll
            for (int r = 0; r < 4; ++r)
                red[(((wave - 1) * 4 + pf) * 64 + lane) * 4 + r] = acc[pf][r];
    }
    __syncthreads();
    if (wave == 0 && (lane >> 4) == 0) {
#pragma unroll
        for (int pf = 0; pf < 4; ++pf) {
            int pl = pf * 16 + cl;
            int x = pl & (TW - 1), y = pl >> 5;
            int px = (rowBase + y) * W + colBase + x;
#pragma unroll
            for (int r = 0; r < 3; ++r) {
                float s = acc[pf][r];
#pragma unroll
                for (int wv = 0; wv < 3; ++wv)
                    s += red[((wv * 4 + pf) * 64 + lane) * 4 + r];
                out[(size_t)(b * 3 + r) * NS + px] = s + rgbb[r];
            }
        }
    }
}

// ---------------- launch ----------------
extern "C" void kernel_launch(void* const* d_in, const int* in_sizes, int n_in,
                              void* d_out, int out_size, void* d_ws, size_t ws_size,
                              hipStream_t stream)
{
    const float* latent = (const float*)d_in[0];
    const float* noise  = (const float*)d_in[1];
    const float* map_w  = (const float*)d_in[2];
    const float* map_b  = (const float*)d_in[3];
    const float* A_w    = (const float*)d_in[4];
    const float* A_b    = (const float*)d_in[5];
    const float* B_w    = (const float*)d_in[6];
    const float* B_b    = (const float*)d_in[7];
    const float* conv_w = (const float*)d_in[8];
    const float* rgb_w  = (const float*)d_in[9];
    const float* rgb_b  = (const float*)d_in[10];
    float* out = (float*)d_out;
    (void)d_ws; (void)ws_size;

    prep_kernel<<<(WPN + RGBN + S2N + 255) / 256, 256, 0, stream>>>(conv_w, rgb_w);

    // mapping: 8 dispatches (layer-serial), pixelnorm fused into layer 0; ends in g_w[0]
    int wsel = 0;
    for (int i = 0; i < LMAP; ++i) {
        map_fc_kernel<<<dim3(8, BS), 256, 0, stream>>>(
            wsel, i == 0 ? 1 : 0, latent, map_w + (size_t)i * D * D, map_b + i * D);
        wsel ^= 1;
    }

    style_rstd_kernel<<<dim3(8, BS), 256, 0, stream>>>(A_w, A_b);

    // layers 1+2 fused (8x8) -> g_bufA
    conv8_pair_kernel<<<BS, 256, 0, stream>>>(noise, B_w, B_b);

    int cur = 0;   // data in g_bufA
    int Hc = 8;
    for (int i = 3; i < NLAYERS; ++i) {
        if (i & 1) Hc *= 2;
        int ns = Hc * Hc;
        int lnext = (i < 8) ? (i + 1) : 0;
        dim3 grid(ns / 64, BS);
        const float* nz = noise + (size_t)i * BS * 4096;
        switch (i) {
            case 3: conv_mfma_kernel<4, 1, 4><<<grid, 256, 0, stream>>>(cur, i, lnext, nz, B_w + i * CCH, B_b + i * CCH); break;
            case 4: conv_mfma_kernel<4, 0, 4><<<grid, 256, 0, stream>>>(cur, i, lnext, nz, B_w + i * CCH, B_b + i * CCH); break;
            case 5: conv_mfma_kernel<5, 1, 5><<<grid, 256, 0, stream>>>(cur, i, lnext, nz, B_w + i * CCH, B_b + i * CCH); break;
            case 6: conv_mfma_kernel<5, 0, 5><<<grid, 256, 0, stream>>>(cur, i, lnext, nz, B_w + i * CCH, B_b + i * CCH); break;
            case 7: conv_mfma_kernel<6, 1, 5><<<grid, 256, 0, stream>>>(cur, i, lnext, nz, B_w + i * CCH, B_b + i * CCH); break;
            case 8: conv_mfma_kernel<6, 0, 5><<<grid, 256, 0, stream>>>(cur, i, lnext, nz, B_w + i * CCH, B_b + i * CCH); break;
        }
        cur ^= 1;
    }

    rgb_mfma_kernel<<<dim3(64, BS), 256, 0, stream>>>(cur, rgb_b, out);
}